// Round 1
// 730.612 us; speedup vs baseline: 1.3971x; 1.3971x over previous
//
#include <hip/hip_runtime.h>

#define T_TOK 4096   // B*S
#define D_DIM 1024
#define N3    3072
#define S_LEN 2048
#define NH    16
#define HD    64
#define KAUG  1056   // 1024 + 16 (q-lora) + 16 (v-lora)

#define OUT_A_ELEMS   4194304   // B*S*D   (f32 elements)
#define OUT_KV_ELEMS  4194304   // B*H*S*hd

typedef __attribute__((ext_vector_type(8))) short bf16x8;
typedef __attribute__((ext_vector_type(4))) float f32x4;

__device__ __forceinline__ unsigned short f2bf(float f) {
    unsigned u = __float_as_uint(f);
    u += 0x7FFFu + ((u >> 16) & 1u);
    return (unsigned short)(u >> 16);
}
__device__ __forceinline__ float bf2f(unsigned short h) {
    return __uint_as_float(((unsigned)h) << 16);
}

#define GLL16(gp, lp) __builtin_amdgcn_global_load_lds( \
    (const __attribute__((address_space(1))) unsigned int*)(gp), \
    (__attribute__((address_space(3))) unsigned int*)(lp), 16, 0, 0)

// ---------------- K1: lora down-proj  tq = x@q_a1, tv = x@v_a1  ----------------
__global__ __launch_bounds__(64) void lora1_kernel(const float* __restrict__ x,
    const float* __restrict__ qa1, const float* __restrict__ va1,
    float* __restrict__ tq, float* __restrict__ tv) {
    int t = blockIdx.x;
    int lane = threadIdx.x;
    if (lane >= 32) return;
    const float* a1 = (lane < 16) ? qa1 : va1;
    int col = lane & 15;
    const float* xr = x + (size_t)t * D_DIM;
    float acc = 0.f;
#pragma unroll 4
    for (int k = 0; k < D_DIM; ++k)
        acc = fmaf(xr[k], a1[k * 16 + col], acc);
    if (lane < 16) tq[t * 16 + col] = acc;
    else           tv[t * 16 + col] = acc;
}

// ---------------- prep: split A_aug = [x | tq | tv] into bf16 hi/lo planes [T_TOK][KAUG]
__global__ __launch_bounds__(256) void splitA_kernel(const float* __restrict__ x,
    const float* __restrict__ tq, const float* __restrict__ tv,
    unsigned short* __restrict__ ah, unsigned short* __restrict__ al) {
    int idx = blockIdx.x * 256 + threadIdx.x;        // float4 index
    const int total = T_TOK * (KAUG / 4);            // 1,081,344
    if (idx >= total) return;
    int t = idx / (KAUG / 4);
    int c4 = (idx - t * (KAUG / 4)) * 4;
    float4 v;
    if (c4 < D_DIM)           v = *(const float4*)&x[(size_t)t * D_DIM + c4];
    else if (c4 < D_DIM + 16) v = *(const float4*)&tq[t * 16 + (c4 - D_DIM)];
    else                      v = *(const float4*)&tv[t * 16 + (c4 - D_DIM - 16)];
    ushort4 h, l;
    h.x = f2bf(v.x); l.x = f2bf(v.x - bf2f(h.x));
    h.y = f2bf(v.y); l.y = f2bf(v.y - bf2f(h.y));
    h.z = f2bf(v.z); l.z = f2bf(v.z - bf2f(h.z));
    h.w = f2bf(v.w); l.w = f2bf(v.w - bf2f(h.w));
    *(ushort4*)&ah[(size_t)t * KAUG + c4] = h;
    *(ushort4*)&al[(size_t)t * KAUG + c4] = l;
}

// ---------------- prep: W_aug^T split planes [N3][KAUG]
// W_aug[k][n]: k<1024 -> c_attn_w; k in [1024,1040) -> 0.5*qa2[k-1024][n] (n<1024 else 0)
//              k in [1040,1056) -> 0.5*va2[k-1040][n-2048] (n>=2048 else 0)
__global__ __launch_bounds__(256) void splitW_kernel(const float* __restrict__ w,
    const float* __restrict__ qa2, const float* __restrict__ va2,
    unsigned short* __restrict__ bh, unsigned short* __restrict__ bl) {
    __shared__ float T[32][65];
    int bn = blockIdx.x;   // 0..47  (64 n-cols)
    int bk = blockIdx.y;   // 0..32  (32 k-rows)
    int tid = threadIdx.x;
#pragma unroll
    for (int u = 0; u < 2; ++u) {
        int id = tid + 256 * u;     // 0..511
        int kr = id >> 4;           // 0..31
        int n4 = (id & 15) * 4;
        int k = bk * 32 + kr;
        int n = bn * 64 + n4;
        float4 v = make_float4(0.f, 0.f, 0.f, 0.f);
        if (k < D_DIM) {
            v = *(const float4*)&w[(size_t)k * N3 + n];
        } else if (k < D_DIM + 16) {
            if (n < D_DIM) {
                float4 q4 = *(const float4*)&qa2[(k - D_DIM) * D_DIM + n];
                v = make_float4(q4.x * 0.5f, q4.y * 0.5f, q4.z * 0.5f, q4.w * 0.5f);
            }
        } else {
            if (n >= 2 * D_DIM) {
                float4 q4 = *(const float4*)&va2[(k - D_DIM - 16) * D_DIM + (n - 2 * D_DIM)];
                v = make_float4(q4.x * 0.5f, q4.y * 0.5f, q4.z * 0.5f, q4.w * 0.5f);
            }
        }
        T[kr][n4 + 0] = v.x; T[kr][n4 + 1] = v.y;
        T[kr][n4 + 2] = v.z; T[kr][n4 + 3] = v.w;
    }
    __syncthreads();
    int n = tid >> 2;            // 0..63
    int k8 = (tid & 3) * 8;      // 0,8,16,24
    unsigned short hh[8], ll[8];
#pragma unroll
    for (int j = 0; j < 8; ++j) {
        float v = T[k8 + j][n];
        hh[j] = f2bf(v);
        ll[j] = f2bf(v - bf2f(hh[j]));
    }
    size_t ro = (size_t)(bn * 64 + n) * KAUG + bk * 32 + k8;
    ushort4 h0, h1, l0, l1;
    h0.x = hh[0]; h0.y = hh[1]; h0.z = hh[2]; h0.w = hh[3];
    h1.x = hh[4]; h1.y = hh[5]; h1.z = hh[6]; h1.w = hh[7];
    l0.x = ll[0]; l0.y = ll[1]; l0.z = ll[2]; l0.w = ll[3];
    l1.x = ll[4]; l1.y = ll[5]; l1.z = ll[6]; l1.w = ll[7];
    *(ushort4*)&bh[ro]     = h0;
    *(ushort4*)&bh[ro + 4] = h1;
    *(ushort4*)&bl[ro]     = l0;
    *(ushort4*)&bl[ro + 4] = l1;
}

// ---------------- K2 (new): split-bf16 MFMA GEMM, lora folded into K, fused scatter
// C[t][n] = sum_k A_aug[t][k] * W_augT[n][k];  128x128 tile, BK=32, 4 waves x (64x64)
__global__ __launch_bounds__(256) void qkv_mfma(
    const unsigned short* __restrict__ ah_g, const unsigned short* __restrict__ al_g,
    const unsigned short* __restrict__ bh_g, const unsigned short* __restrict__ bl_g,
    const float* __restrict__ bias,
    float* __restrict__ qstage, float* __restrict__ pres) {
    __shared__ unsigned short Ah[128 * 32], Al[128 * 32], Bh[128 * 32], Bl[128 * 32];
    int bn = blockIdx.x;   // 0..23
    int bm = blockIdx.y;   // 0..31
    int tid = threadIdx.x;
    int w = tid >> 6, l = tid & 63;
    int wr = w >> 1, wc = w & 1;

    f32x4 acc[4][4];
#pragma unroll
    for (int i = 0; i < 4; ++i)
#pragma unroll
        for (int j = 0; j < 4; ++j)
            acc[i][j] = (f32x4){0.f, 0.f, 0.f, 0.f};

    // staging: wave w stages tile rows [w*32, w*32+32) in two 16-row chunks.
    // HW semantics: LDS dst = wave-uniform base + lane*16; tile row stride 64B
    // -> lane covers row (l>>2), k-bytes (l&3)*16  == global k offset (l&3)*8 elems.
    int srow = l >> 2;
    int sk = (l & 3) * 8;
    const size_t a_base0 = (size_t)(bm * 128 + w * 32 + srow) * KAUG + sk;
    const size_t a_base1 = a_base0 + (size_t)16 * KAUG;
    const size_t b_base0 = (size_t)(bn * 128 + w * 32 + srow) * KAUG + sk;
    const size_t b_base1 = b_base0 + (size_t)16 * KAUG;
    unsigned short* pAh0 = &Ah[(w * 32) * 32];
    unsigned short* pAh1 = &Ah[(w * 32 + 16) * 32];
    unsigned short* pAl0 = &Al[(w * 32) * 32];
    unsigned short* pAl1 = &Al[(w * 32 + 16) * 32];
    unsigned short* pBh0 = &Bh[(w * 32) * 32];
    unsigned short* pBh1 = &Bh[(w * 32 + 16) * 32];
    unsigned short* pBl0 = &Bl[(w * 32) * 32];
    unsigned short* pBl1 = &Bl[(w * 32 + 16) * 32];

    int lrow = l & 15;
    int lq = (l >> 4) * 8;

    for (int k0 = 0; k0 < KAUG; k0 += 32) {
        __syncthreads();   // all waves done reading LDS from previous step
        GLL16(ah_g + a_base0 + k0, pAh0);
        GLL16(ah_g + a_base1 + k0, pAh1);
        GLL16(al_g + a_base0 + k0, pAl0);
        GLL16(al_g + a_base1 + k0, pAl1);
        GLL16(bh_g + b_base0 + k0, pBh0);
        GLL16(bh_g + b_base1 + k0, pBh1);
        GLL16(bl_g + b_base0 + k0, pBl0);
        GLL16(bl_g + b_base1 + k0, pBl1);
        __syncthreads();   // compiler drains vmcnt(0) before barrier -> LDS valid

        bf16x8 fa_h[4], fa_l[4], fb_h[4], fb_l[4];
#pragma unroll
        for (int i = 0; i < 4; ++i) {
            int ro = (wr * 64 + i * 16 + lrow) * 32 + lq;
            fa_h[i] = *(const bf16x8*)&Ah[ro];
            fa_l[i] = *(const bf16x8*)&Al[ro];
        }
#pragma unroll
        for (int j = 0; j < 4; ++j) {
            int ro = (wc * 64 + j * 16 + lrow) * 32 + lq;
            fb_h[j] = *(const bf16x8*)&Bh[ro];
            fb_l[j] = *(const bf16x8*)&Bl[ro];
        }
#pragma unroll
        for (int i = 0; i < 4; ++i)
#pragma unroll
            for (int j = 0; j < 4; ++j) {
                acc[i][j] = __builtin_amdgcn_mfma_f32_16x16x32_bf16(
                    fa_h[i], fb_h[j], acc[i][j], 0, 0, 0);
                acc[i][j] = __builtin_amdgcn_mfma_f32_16x16x32_bf16(
                    fa_h[i], fb_l[j], acc[i][j], 0, 0, 0);
                acc[i][j] = __builtin_amdgcn_mfma_f32_16x16x32_bf16(
                    fa_l[i], fb_h[j], acc[i][j], 0, 0, 0);
            }
    }

    // epilogue: bias, q-scale(1/8), scatter to [B,H,S,hd]
    int seg = bn >> 3;   // 0=q, 1=k, 2=v  (BN=128 never straddles a 1024 segment)
#pragma unroll
    for (int j = 0; j < 4; ++j) {
        int n = bn * 128 + wc * 64 + j * 16 + lrow;   // C-frag: col = lane&15
        float bz = bias[n];
        int h = (n >> 6) & 15;
        int d = n & 63;
#pragma unroll
        for (int i = 0; i < 4; ++i) {
            int tbase = bm * 128 + wr * 64 + i * 16 + (l >> 4) * 4;  // row=(l>>4)*4+reg
#pragma unroll
            for (int r = 0; r < 4; ++r) {
                int t = tbase + r;
                float v = acc[i][j][r] + bz;
                int bb = t >> 11, s = t & 2047;
                size_t idx = (((size_t)(bb * NH + h) * S_LEN + s) * HD) + d;
                if (seg == 0)      qstage[idx] = v * 0.125f;
                else if (seg == 1) pres[idx] = v;
                else               pres[OUT_KV_ELEMS + idx] = v;
            }
        }
    }
}

// ------ K2 fallback (old fp32 path, used only if ws_size is too small) ------
__global__ __launch_bounds__(256) void qkv_kernel(const float* __restrict__ x,
    const float* __restrict__ w, const float* __restrict__ bias,
    const float* __restrict__ qa2, const float* __restrict__ va2,
    const float* __restrict__ tq, const float* __restrict__ tv,
    float* __restrict__ qstage, float* __restrict__ pres) {
    __shared__ float As[128][17];
    __shared__ float Bs[16][64];
    int bx = blockIdx.x;
    int by = blockIdx.y;
    int tid = threadIdx.x;
    int tx = tid & 15, ty = tid >> 4;

    float c[8][4];
#pragma unroll
    for (int i = 0; i < 8; ++i)
#pragma unroll
        for (int j = 0; j < 4; ++j) c[i][j] = 0.f;

    for (int k0 = 0; k0 < D_DIM; k0 += 16) {
#pragma unroll
        for (int u = 0; u < 2; ++u) {
            int f4 = tid + 256 * u;
            int row = f4 >> 2;
            int kk4 = (f4 & 3) * 4;
            float4 av = *(const float4*)&x[(size_t)(by * 128 + row) * D_DIM + k0 + kk4];
            As[row][kk4 + 0] = av.x; As[row][kk4 + 1] = av.y;
            As[row][kk4 + 2] = av.z; As[row][kk4 + 3] = av.w;
        }
        {
            int kkb = tid >> 4;
            int col4 = (tid & 15) * 4;
            *(float4*)&Bs[kkb][col4] =
                *(const float4*)&w[(size_t)(k0 + kkb) * N3 + bx * 64 + col4];
        }
        __syncthreads();
#pragma unroll
        for (int kk = 0; kk < 16; ++kk) {
            float4 bv = *(const float4*)&Bs[kk][tx * 4];
#pragma unroll
            for (int i = 0; i < 8; ++i) {
                float a = As[ty * 8 + i][kk];
                c[i][0] = fmaf(a, bv.x, c[i][0]);
                c[i][1] = fmaf(a, bv.y, c[i][1]);
                c[i][2] = fmaf(a, bv.z, c[i][2]);
                c[i][3] = fmaf(a, bv.w, c[i][3]);
            }
        }
        __syncthreads();
    }

    int seg = bx >> 4;
    int h = bx & 15;
    int ncol = bx * 64 + tx * 4;
    float4 bias4 = *(const float4*)&bias[ncol];
    int nloc = h * 64 + tx * 4;

    float4 arr[16];
    if (seg != 1) {
        const float* a2 = (seg == 0 ? qa2 : va2);
#pragma unroll
        for (int jj = 0; jj < 16; ++jj)
            arr[jj] = *(const float4*)&a2[jj * D_DIM + nloc];
    }

#pragma unroll
    for (int i = 0; i < 8; ++i) {
        int t = by * 128 + ty * 8 + i;
        float v0 = c[i][0] + bias4.x;
        float v1 = c[i][1] + bias4.y;
        float v2 = c[i][2] + bias4.z;
        float v3 = c[i][3] + bias4.w;
        if (seg != 1) {
            const float* trow = (seg == 0 ? tq : tv) + t * 16;
            float l0 = 0.f, l1 = 0.f, l2 = 0.f, l3 = 0.f;
#pragma unroll
            for (int jj = 0; jj < 16; ++jj) {
                float tvv = trow[jj];
                l0 = fmaf(tvv, arr[jj].x, l0);
                l1 = fmaf(tvv, arr[jj].y, l1);
                l2 = fmaf(tvv, arr[jj].z, l2);
                l3 = fmaf(tvv, arr[jj].w, l3);
            }
            v0 += 0.5f * l0; v1 += 0.5f * l1; v2 += 0.5f * l2; v3 += 0.5f * l3;
        }
        int b = t >> 11, sidx = t & 2047;
        size_t idx = (((size_t)(b * NH + h) * S_LEN + sidx) * HD) + tx * 4;
        if (seg == 0) {
            *(float4*)&qstage[idx] = make_float4(v0 * 0.125f, v1 * 0.125f,
                                                 v2 * 0.125f, v3 * 0.125f);
        } else if (seg == 1) {
            *(float4*)&pres[idx] = make_float4(v0, v1, v2, v3);
        } else {
            *(float4*)&pres[OUT_KV_ELEMS + idx] = make_float4(v0, v1, v2, v3);
        }
    }
}

// ---------------- K3: flash attention, LDS-GEMM tiles ----------------
#define LSTR 68
__global__ __launch_bounds__(256) void attn_kernel(const float* __restrict__ q_s,
    const float* __restrict__ k_s, const float* __restrict__ v_s,
    float* __restrict__ a_s) {
    __shared__ float Qt[64][LSTR];
    __shared__ float KP[64][LSTR];
    __shared__ float Vs[64][LSTR];
    int bh = blockIdx.x;
    int qi = 31 - blockIdx.y;
    int tid = threadIdx.x;
    int tx = tid & 15, ty = tid >> 4;

#pragma unroll
    for (int qq = 0; qq < 4; ++qq) {
        int q  = qq * 16 + (tid >> 4);
        int d4 = (tid & 15) * 4;
        float4 v = *(const float4*)&q_s[((size_t)bh * S_LEN + qi * 64 + q) * HD + d4];
        Qt[d4 + 0][q] = v.x; Qt[d4 + 1][q] = v.y;
        Qt[d4 + 2][q] = v.z; Qt[d4 + 3][q] = v.w;
    }

    float o[4][4];
#pragma unroll
    for (int r = 0; r < 4; ++r)
#pragma unroll
        for (int c = 0; c < 4; ++c) o[r][c] = 0.f;
    float mrow[4] = {-1e30f, -1e30f, -1e30f, -1e30f};
    float lrow[4] = {0.f, 0.f, 0.f, 0.f};

    for (int kt = 0; kt <= qi; ++kt) {
        __syncthreads();
#pragma unroll
        for (int kk2 = 0; kk2 < 4; ++kk2) {
            int k  = kk2 * 16 + (tid >> 4);
            int d4 = (tid & 15) * 4;
            size_t rowoff = ((size_t)bh * S_LEN + kt * 64 + k) * HD + d4;
            float4 kv4 = *(const float4*)&k_s[rowoff];
            KP[d4 + 0][k] = kv4.x; KP[d4 + 1][k] = kv4.y;
            KP[d4 + 2][k] = kv4.z; KP[d4 + 3][k] = kv4.w;
            float4 vv4 = *(const float4*)&v_s[rowoff];
            *(float4*)&Vs[k][d4] = vv4;
        }
        __syncthreads();

        float s[4][4];
#pragma unroll
        for (int r = 0; r < 4; ++r)
#pragma unroll
            for (int c = 0; c < 4; ++c) s[r][c] = 0.f;
#pragma unroll 8
        for (int d = 0; d < 64; ++d) {
            float4 qv = *(const float4*)&Qt[d][ty * 4];
            float4 kv = *(const float4*)&KP[d][tx * 4];
            float qa[4] = {qv.x, qv.y, qv.z, qv.w};
            float ka[4] = {kv.x, kv.y, kv.z, kv.w};
#pragma unroll
            for (int r = 0; r < 4; ++r)
#pragma unroll
                for (int c = 0; c < 4; ++c)
                    s[r][c] = fmaf(qa[r], ka[c], s[r][c]);
        }
        if (kt == qi) {
#pragma unroll
            for (int r = 0; r < 4; ++r)
#pragma unroll
                for (int c = 0; c < 4; ++c)
                    if (tx * 4 + c > ty * 4 + r) s[r][c] = -1e30f;
        }
        __syncthreads();

        float p[4][4];
#pragma unroll
        for (int r = 0; r < 4; ++r) {
            float mx = fmaxf(fmaxf(s[r][0], s[r][1]), fmaxf(s[r][2], s[r][3]));
            mx = fmaxf(mx, __shfl_xor(mx, 1));
            mx = fmaxf(mx, __shfl_xor(mx, 2));
            mx = fmaxf(mx, __shfl_xor(mx, 4));
            mx = fmaxf(mx, __shfl_xor(mx, 8));
            float mn = fmaxf(mrow[r], mx);
            float alpha = __expf(mrow[r] - mn);
            mrow[r] = mn;
            float rs = 0.f;
#pragma unroll
            for (int c = 0; c < 4; ++c) {
                p[r][c] = __expf(s[r][c] - mn);
                rs += p[r][c];
            }
            rs += __shfl_xor(rs, 1);
            rs += __shfl_xor(rs, 2);
            rs += __shfl_xor(rs, 4);
            rs += __shfl_xor(rs, 8);
            lrow[r] = lrow[r] * alpha + rs;
#pragma unroll
            for (int c = 0; c < 4; ++c) o[r][c] *= alpha;
            *(float4*)&KP[ty * 4 + r][tx * 4] =
                make_float4(p[r][0], p[r][1], p[r][2], p[r][3]);
        }
        __syncthreads();

#pragma unroll 8
        for (int k = 0; k < 64; ++k) {
            float4 vv = *(const float4*)&Vs[k][tx * 4];
            float va[4] = {vv.x, vv.y, vv.z, vv.w};
#pragma unroll
            for (int r = 0; r < 4; ++r) {
                float pr = KP[ty * 4 + r][k];
#pragma unroll
                for (int c = 0; c < 4; ++c)
                    o[r][c] = fmaf(pr, va[c], o[r][c]);
            }
        }
    }

    int b = bh >> 4, h = bh & 15;
#pragma unroll
    for (int r = 0; r < 4; ++r) {
        int i = qi * 64 + ty * 4 + r;
        float inv = 1.f / lrow[r];
        *(float4*)&a_s[((size_t)(b * S_LEN + i)) * D_DIM + h * HD + tx * 4] =
            make_float4(o[r][0] * inv, o[r][1] * inv, o[r][2] * inv, o[r][3] * inv);
    }
}

// ---------------- K4: out = a_s @ c_proj_w + c_proj_b  -> f32 ----------------
__global__ __launch_bounds__(256) void proj_kernel(const float* __restrict__ A,
    const float* __restrict__ w, const float* __restrict__ bias,
    float* __restrict__ outp) {
    __shared__ float As[128][17];
    __shared__ float Bs[16][64];
    int bx = blockIdx.x;
    int by = blockIdx.y;
    int tid = threadIdx.x;
    int tx = tid & 15, ty = tid >> 4;

    float c[8][4];
#pragma unroll
    for (int i = 0; i < 8; ++i)
#pragma unroll
        for (int j = 0; j < 4; ++j) c[i][j] = 0.f;

    for (int k0 = 0; k0 < D_DIM; k0 += 16) {
#pragma unroll
        for (int u = 0; u < 2; ++u) {
            int f4 = tid + 256 * u;
            int row = f4 >> 2;
            int kk4 = (f4 & 3) * 4;
            float4 av = *(const float4*)&A[(size_t)(by * 128 + row) * D_DIM + k0 + kk4];
            As[row][kk4 + 0] = av.x; As[row][kk4 + 1] = av.y;
            As[row][kk4 + 2] = av.z; As[row][kk4 + 3] = av.w;
        }
        {
            int kkb = tid >> 4;
            int col4 = (tid & 15) * 4;
            *(float4*)&Bs[kkb][col4] =
                *(const float4*)&w[(size_t)(k0 + kkb) * D_DIM + bx * 64 + col4];
        }
        __syncthreads();
#pragma unroll
        for (int kk = 0; kk < 16; ++kk) {
            float4 bv = *(const float4*)&Bs[kk][tx * 4];
#pragma unroll
            for (int i = 0; i < 8; ++i) {
                float a = As[ty * 8 + i][kk];
                c[i][0] = fmaf(a, bv.x, c[i][0]);
                c[i][1] = fmaf(a, bv.y, c[i][1]);
                c[i][2] = fmaf(a, bv.z, c[i][2]);
                c[i][3] = fmaf(a, bv.w, c[i][3]);
            }
        }
        __syncthreads();
    }

    int ncol = bx * 64 + tx * 4;
    float4 bias4 = *(const float4*)&bias[ncol];
#pragma unroll
    for (int i = 0; i < 8; ++i) {
        int t = by * 128 + ty * 8 + i;
        *(float4*)&outp[(size_t)t * D_DIM + ncol] =
            make_float4(c[i][0] + bias4.x, c[i][1] + bias4.y,
                        c[i][2] + bias4.z, c[i][3] + bias4.w);
    }
}

extern "C" void kernel_launch(void* const* d_in, const int* in_sizes, int n_in,
                              void* d_out, int out_size, void* d_ws, size_t ws_size,
                              hipStream_t stream) {
    const float* x        = (const float*)d_in[0];
    const float* c_attn_w = (const float*)d_in[1];
    const float* c_attn_b = (const float*)d_in[2];
    const float* c_proj_w = (const float*)d_in[3];
    const float* c_proj_b = (const float*)d_in[4];
    const float* q_a1     = (const float*)d_in[5];
    const float* q_a2     = (const float*)d_in[6];
    const float* v_a1     = (const float*)d_in[7];
    const float* v_a2     = (const float*)d_in[8];

    float* outf   = (float*)d_out;
    float* qstage = outf;                  // a-region reused as f32 q staging [B,H,S,hd]
    float* pres   = outf + OUT_A_ELEMS;    // present [2,B,H,S,hd] f32

    // workspace layout (bytes):
    //   [0, 256K)        tq
    //   [256K, 512K)     tv
    //   [512K, +6.19M)   wt_hi [N3][KAUG] bf16
    //   [.., +6.19M)     wt_lo
    //   [13,500,416 ..)  a_hi [T_TOK][KAUG] bf16 (8,650,752 B)
    //   [.., ..)         a_lo (8,650,752 B)
    //   a_s (16 MB f32) aliases the a_hi/a_lo region after the GEMM consumed it
    char* wsb = (char*)d_ws;
    float* tq = (float*)wsb;
    float* tv = (float*)(wsb + 262144);
    unsigned short* wt_hi = (unsigned short*)(wsb + 524288);
    unsigned short* wt_lo = (unsigned short*)(wsb + 524288 + 6488064);
    unsigned short* a_hi  = (unsigned short*)(wsb + 13500416);
    unsigned short* a_lo  = (unsigned short*)(wsb + 13500416 + 8650752);
    float* a_s = (float*)(wsb + 13500416);
    const size_t WS_NEED = 13500416 + 2 * 8650752;   // 30,801,920 B

    lora1_kernel<<<dim3(T_TOK), dim3(64), 0, stream>>>(x, q_a1, v_a1, tq, tv);

    if (ws_size >= WS_NEED) {
        splitA_kernel<<<dim3((T_TOK * (KAUG / 4) + 255) / 256), dim3(256), 0, stream>>>(
            x, tq, tv, a_hi, a_lo);
        splitW_kernel<<<dim3(48, KAUG / 32), dim3(256), 0, stream>>>(
            c_attn_w, q_a2, v_a2, wt_hi, wt_lo);
        qkv_mfma<<<dim3(24, 32), dim3(256), 0, stream>>>(
            a_hi, a_lo, wt_hi, wt_lo, c_attn_b, qstage, pres);
        attn_kernel<<<dim3(32, 32), dim3(256), 0, stream>>>(
            qstage, pres, pres + OUT_KV_ELEMS, a_s);
        proj_kernel<<<dim3(16, 32), dim3(256), 0, stream>>>(
            a_s, c_proj_w, c_proj_b, outf);
    } else {
        // fallback: old fp32 path (needs only tq+tv+a_s)
        float* a_s2 = tv + 65536;
        qkv_kernel<<<dim3(48, 32), dim3(256), 0, stream>>>(x, c_attn_w, c_attn_b,
            q_a2, v_a2, tq, tv, qstage, pres);
        attn_kernel<<<dim3(32, 32), dim3(256), 0, stream>>>(
            qstage, pres, pres + OUT_KV_ELEMS, a_s2);
        proj_kernel<<<dim3(16, 32), dim3(256), 0, stream>>>(
            a_s2, c_proj_w, c_proj_b, outf);
    }
}

// Round 2
// 542.730 us; speedup vs baseline: 1.8807x; 1.3462x over previous
//
#include <hip/hip_runtime.h>

#define T_TOK 4096   // B*S
#define D_DIM 1024
#define N3    3072
#define S_LEN 2048
#define NH    16
#define HD    64
#define KAUG  1056   // 1024 + 16 (q-lora) + 16 (v-lora)

#define OUT_A_ELEMS   4194304   // B*S*D   (f32 elements)
#define OUT_KV_ELEMS  4194304   // B*H*S*hd

typedef __attribute__((ext_vector_type(8))) short bf16x8;
typedef __attribute__((ext_vector_type(4))) float f32x4;
typedef __attribute__((ext_vector_type(16))) float f32x16;

union U4 { unsigned u[4]; bf16x8 v; };

__device__ __forceinline__ unsigned short f2bf(float f) {
    unsigned u = __float_as_uint(f);
    u += 0x7FFFu + ((u >> 16) & 1u);
    return (unsigned short)(u >> 16);
}
__device__ __forceinline__ float bf2f(unsigned short h) {
    return __uint_as_float(((unsigned)h) << 16);
}
__device__ __forceinline__ unsigned cvtpk(float a, float b) {
    unsigned r;
    asm("v_cvt_pk_bf16_f32 %0, %1, %2" : "=v"(r) : "v"(a), "v"(b));
    return r;
}

#define GLL16(gp, lp) __builtin_amdgcn_global_load_lds( \
    (const __attribute__((address_space(1))) unsigned int*)(gp), \
    (__attribute__((address_space(3))) unsigned int*)(lp), 16, 0, 0)

#define MFMA32(A, B, C) __builtin_amdgcn_mfma_f32_32x32x16_bf16(A, B, C, 0, 0, 0)

// ---------------- K1: lora down-proj  tq = x@q_a1, tv = x@v_a1  ----------------
__global__ __launch_bounds__(64) void lora1_kernel(const float* __restrict__ x,
    const float* __restrict__ qa1, const float* __restrict__ va1,
    float* __restrict__ tq, float* __restrict__ tv) {
    int t = blockIdx.x;
    int lane = threadIdx.x;
    if (lane >= 32) return;
    const float* a1 = (lane < 16) ? qa1 : va1;
    int col = lane & 15;
    const float* xr = x + (size_t)t * D_DIM;
    float acc = 0.f;
#pragma unroll 4
    for (int k = 0; k < D_DIM; ++k)
        acc = fmaf(xr[k], a1[k * 16 + col], acc);
    if (lane < 16) tq[t * 16 + col] = acc;
    else           tv[t * 16 + col] = acc;
}

// ---------------- prep: split A_aug = [x | tq | tv] into bf16 hi/lo planes [T_TOK][KAUG]
__global__ __launch_bounds__(256) void splitA_kernel(const float* __restrict__ x,
    const float* __restrict__ tq, const float* __restrict__ tv,
    unsigned short* __restrict__ ah, unsigned short* __restrict__ al) {
    int idx = blockIdx.x * 256 + threadIdx.x;        // float4 index
    const int total = T_TOK * (KAUG / 4);
    if (idx >= total) return;
    int t = idx / (KAUG / 4);
    int c4 = (idx - t * (KAUG / 4)) * 4;
    float4 v;
    if (c4 < D_DIM)           v = *(const float4*)&x[(size_t)t * D_DIM + c4];
    else if (c4 < D_DIM + 16) v = *(const float4*)&tq[t * 16 + (c4 - D_DIM)];
    else                      v = *(const float4*)&tv[t * 16 + (c4 - D_DIM - 16)];
    ushort4 h, l;
    h.x = f2bf(v.x); l.x = f2bf(v.x - bf2f(h.x));
    h.y = f2bf(v.y); l.y = f2bf(v.y - bf2f(h.y));
    h.z = f2bf(v.z); l.z = f2bf(v.z - bf2f(h.z));
    h.w = f2bf(v.w); l.w = f2bf(v.w - bf2f(h.w));
    *(ushort4*)&ah[(size_t)t * KAUG + c4] = h;
    *(ushort4*)&al[(size_t)t * KAUG + c4] = l;
}

// ---------------- prep: W_aug^T split planes [N3][KAUG]
__global__ __launch_bounds__(256) void splitW_kernel(const float* __restrict__ w,
    const float* __restrict__ qa2, const float* __restrict__ va2,
    unsigned short* __restrict__ bh, unsigned short* __restrict__ bl) {
    __shared__ float T[32][65];
    int bn = blockIdx.x;
    int bk = blockIdx.y;
    int tid = threadIdx.x;
#pragma unroll
    for (int u = 0; u < 2; ++u) {
        int id = tid + 256 * u;
        int kr = id >> 4;
        int n4 = (id & 15) * 4;
        int k = bk * 32 + kr;
        int n = bn * 64 + n4;
        float4 v = make_float4(0.f, 0.f, 0.f, 0.f);
        if (k < D_DIM) {
            v = *(const float4*)&w[(size_t)k * N3 + n];
        } else if (k < D_DIM + 16) {
            if (n < D_DIM) {
                float4 q4 = *(const float4*)&qa2[(k - D_DIM) * D_DIM + n];
                v = make_float4(q4.x * 0.5f, q4.y * 0.5f, q4.z * 0.5f, q4.w * 0.5f);
            }
        } else {
            if (n >= 2 * D_DIM) {
                float4 q4 = *(const float4*)&va2[(k - D_DIM - 16) * D_DIM + (n - 2 * D_DIM)];
                v = make_float4(q4.x * 0.5f, q4.y * 0.5f, q4.z * 0.5f, q4.w * 0.5f);
            }
        }
        T[kr][n4 + 0] = v.x; T[kr][n4 + 1] = v.y;
        T[kr][n4 + 2] = v.z; T[kr][n4 + 3] = v.w;
    }
    __syncthreads();
    int n = tid >> 2;
    int k8 = (tid & 3) * 8;
    unsigned short hh[8], ll[8];
#pragma unroll
    for (int j = 0; j < 8; ++j) {
        float v = T[k8 + j][n];
        hh[j] = f2bf(v);
        ll[j] = f2bf(v - bf2f(hh[j]));
    }
    size_t ro = (size_t)(bn * 64 + n) * KAUG + bk * 32 + k8;
    ushort4 h0, h1, l0, l1;
    h0.x = hh[0]; h0.y = hh[1]; h0.z = hh[2]; h0.w = hh[3];
    h1.x = hh[4]; h1.y = hh[5]; h1.z = hh[6]; h1.w = hh[7];
    l0.x = ll[0]; l0.y = ll[1]; l0.z = ll[2]; l0.w = ll[3];
    l1.x = ll[4]; l1.y = ll[5]; l1.z = ll[6]; l1.w = ll[7];
    *(ushort4*)&bh[ro]     = h0;
    *(ushort4*)&bh[ro + 4] = h1;
    *(ushort4*)&bl[ro]     = l0;
    *(ushort4*)&bl[ro + 4] = l1;
}

// ---------------- K2: split-bf16 MFMA GEMM, lora folded into K, fused scatter
__global__ __launch_bounds__(256) void qkv_mfma(
    const unsigned short* __restrict__ ah_g, const unsigned short* __restrict__ al_g,
    const unsigned short* __restrict__ bh_g, const unsigned short* __restrict__ bl_g,
    const float* __restrict__ bias,
    float* __restrict__ qstage, float* __restrict__ pres) {
    __shared__ unsigned short Ah[128 * 32], Al[128 * 32], Bh[128 * 32], Bl[128 * 32];
    int bn = blockIdx.x;
    int bm = blockIdx.y;
    int tid = threadIdx.x;
    int w = tid >> 6, l = tid & 63;
    int wr = w >> 1, wc = w & 1;

    f32x4 acc[4][4];
#pragma unroll
    for (int i = 0; i < 4; ++i)
#pragma unroll
        for (int j = 0; j < 4; ++j)
            acc[i][j] = (f32x4){0.f, 0.f, 0.f, 0.f};

    int srow = l >> 2;
    int sk = (l & 3) * 8;
    const size_t a_base0 = (size_t)(bm * 128 + w * 32 + srow) * KAUG + sk;
    const size_t a_base1 = a_base0 + (size_t)16 * KAUG;
    const size_t b_base0 = (size_t)(bn * 128 + w * 32 + srow) * KAUG + sk;
    const size_t b_base1 = b_base0 + (size_t)16 * KAUG;
    unsigned short* pAh0 = &Ah[(w * 32) * 32];
    unsigned short* pAh1 = &Ah[(w * 32 + 16) * 32];
    unsigned short* pAl0 = &Al[(w * 32) * 32];
    unsigned short* pAl1 = &Al[(w * 32 + 16) * 32];
    unsigned short* pBh0 = &Bh[(w * 32) * 32];
    unsigned short* pBh1 = &Bh[(w * 32 + 16) * 32];
    unsigned short* pBl0 = &Bl[(w * 32) * 32];
    unsigned short* pBl1 = &Bl[(w * 32 + 16) * 32];

    int lrow = l & 15;
    int lq = (l >> 4) * 8;

    for (int k0 = 0; k0 < KAUG; k0 += 32) {
        __syncthreads();
        GLL16(ah_g + a_base0 + k0, pAh0);
        GLL16(ah_g + a_base1 + k0, pAh1);
        GLL16(al_g + a_base0 + k0, pAl0);
        GLL16(al_g + a_base1 + k0, pAl1);
        GLL16(bh_g + b_base0 + k0, pBh0);
        GLL16(bh_g + b_base1 + k0, pBh1);
        GLL16(bl_g + b_base0 + k0, pBl0);
        GLL16(bl_g + b_base1 + k0, pBl1);
        __syncthreads();

        bf16x8 fa_h[4], fa_l[4], fb_h[4], fb_l[4];
#pragma unroll
        for (int i = 0; i < 4; ++i) {
            int ro = (wr * 64 + i * 16 + lrow) * 32 + lq;
            fa_h[i] = *(const bf16x8*)&Ah[ro];
            fa_l[i] = *(const bf16x8*)&Al[ro];
        }
#pragma unroll
        for (int j = 0; j < 4; ++j) {
            int ro = (wc * 64 + j * 16 + lrow) * 32 + lq;
            fb_h[j] = *(const bf16x8*)&Bh[ro];
            fb_l[j] = *(const bf16x8*)&Bl[ro];
        }
#pragma unroll
        for (int i = 0; i < 4; ++i)
#pragma unroll
            for (int j = 0; j < 4; ++j) {
                acc[i][j] = __builtin_amdgcn_mfma_f32_16x16x32_bf16(
                    fa_h[i], fb_h[j], acc[i][j], 0, 0, 0);
                acc[i][j] = __builtin_amdgcn_mfma_f32_16x16x32_bf16(
                    fa_h[i], fb_l[j], acc[i][j], 0, 0, 0);
                acc[i][j] = __builtin_amdgcn_mfma_f32_16x16x32_bf16(
                    fa_l[i], fb_h[j], acc[i][j], 0, 0, 0);
            }
    }

    int seg = bn >> 3;
#pragma unroll
    for (int j = 0; j < 4; ++j) {
        int n = bn * 128 + wc * 64 + j * 16 + lrow;
        float bz = bias[n];
        int h = (n >> 6) & 15;
        int d = n & 63;
#pragma unroll
        for (int i = 0; i < 4; ++i) {
            int tbase = bm * 128 + wr * 64 + i * 16 + (l >> 4) * 4;
#pragma unroll
            for (int r = 0; r < 4; ++r) {
                int t = tbase + r;
                float v = acc[i][j][r] + bz;
                int bb = t >> 11, s = t & 2047;
                size_t idx = (((size_t)(bb * NH + h) * S_LEN + s) * HD) + d;
                if (seg == 0)      qstage[idx] = v * 0.125f;
                else if (seg == 1) pres[idx] = v;
                else               pres[OUT_KV_ELEMS + idx] = v;
            }
        }
    }
}

// ---------------- prep: K rows -> swizzled bf16 hi/lo planes [bh][key][64]
// granule (8 elems) at position p holds source granule p ^ (key&7)
__global__ __launch_bounds__(256) void kprep_kernel(const float* __restrict__ kin,
    unsigned short* __restrict__ khp, unsigned short* __restrict__ klp) {
    int id = blockIdx.x * 256 + threadIdx.x;   // 524288 granules
    int rowi = id >> 3;                        // bh*2048 + key
    int gsrc = id & 7;
    const float* src = kin + (size_t)rowi * 64 + gsrc * 8;
    float4 v0 = *(const float4*)src;
    float4 v1 = *(const float4*)(src + 4);
    int key = rowi & 2047;
    int gp = gsrc ^ (key & 7);
    size_t dst = (size_t)rowi * 64 + gp * 8;
    float vv[8] = {v0.x, v0.y, v0.z, v0.w, v1.x, v1.y, v1.z, v1.w};
    bf16x8 h, lo;
#pragma unroll
    for (int j = 0; j < 8; ++j) {
        unsigned short hh = f2bf(vv[j]);
        h[j] = (short)hh;
        lo[j] = (short)f2bf(vv[j] - bf2f(hh));
    }
    *(bf16x8*)&khp[dst] = h;
    *(bf16x8*)&klp[dst] = lo;
}

// ---------------- prep: V -> transposed swizzled bf16 hi/lo planes [bh][d][key]
// within each 64-key tile segment, granule position p holds source granule p ^ (d&7)
__global__ __launch_bounds__(256) void vtprep_kernel(const float* __restrict__ vin,
    unsigned short* __restrict__ vth, unsigned short* __restrict__ vtl) {
    __shared__ __align__(16) unsigned short Th[64][72];
    __shared__ __align__(16) unsigned short Tl[64][72];
    int bh = blockIdx.x;
    int kv0 = blockIdx.y * 64;
    int tid = threadIdx.x;
#pragma unroll
    for (int p = 0; p < 4; ++p) {
        int key = (tid >> 4) + 16 * p;
        int d0 = (tid & 15) * 4;
        float4 v = *(const float4*)&vin[((size_t)bh * 2048 + kv0 + key) * 64 + d0];
        float vv[4] = {v.x, v.y, v.z, v.w};
#pragma unroll
        for (int j = 0; j < 4; ++j) {
            unsigned short hh = f2bf(vv[j]);
            Th[d0 + j][key] = hh;
            Tl[d0 + j][key] = f2bf(vv[j] - bf2f(hh));
        }
    }
    __syncthreads();
    int d = tid >> 2;
#pragma unroll
    for (int q = 0; q < 2; ++q) {
        int gg = (tid & 3) + 4 * q;
        int gs = gg ^ (d & 7);
        bf16x8 hv = *(const bf16x8*)&Th[d][gs * 8];
        bf16x8 lv = *(const bf16x8*)&Tl[d][gs * 8];
        size_t dst = ((size_t)bh * 64 + d) * 2048 + kv0 + gg * 8;
        *(bf16x8*)&vth[dst] = hv;
        *(bf16x8*)&vtl[dst] = lv;
    }
}

// ---------------- K3 (new): MFMA flash attention, 32x32x16, swapped QK^T ----------------
// Block 256 thr = 4 waves; QBLK=128 (32 q/wave); KV tiles of 64 double-buffered.
// K split hi/lo (2-term QK), V split hi/lo (2-term PV); Q, P single bf16.
__device__ __forceinline__ void stage_tile(
    const unsigned short* __restrict__ kh, const unsigned short* __restrict__ kl,
    const unsigned short* __restrict__ vh, const unsigned short* __restrict__ vl,
    unsigned short (*ldsb)[4096], int w, int l, int bh, int kv0) {
    if (w < 2) {
        const unsigned short* gp = (w == 0 ? kh : kl)
            + ((size_t)bh * 2048 + kv0 + (l >> 3)) * 64 + (l & 7) * 8;
        unsigned short* lp = ldsb[w];
#pragma unroll
        for (int i = 0; i < 8; ++i)
            GLL16(gp + i * 512, lp + i * 512);
    } else {
        const unsigned short* gp = (w == 2 ? vh : vl)
            + ((size_t)bh * 64 + (l >> 3)) * 2048 + kv0 + (l & 7) * 8;
        unsigned short* lp = ldsb[w];
#pragma unroll
        for (int i = 0; i < 8; ++i)
            GLL16(gp + (size_t)i * 16384, lp + i * 512);
    }
}

#define QROW(r) ((((r) & 3) + 8 * ((r) >> 2)) + 4 * g)

__global__ __launch_bounds__(256, 2) void attn_mfma(
    const float* __restrict__ q_s,
    const unsigned short* __restrict__ kh, const unsigned short* __restrict__ kl,
    const unsigned short* __restrict__ vh, const unsigned short* __restrict__ vl,
    float* __restrict__ a_s) {
    __shared__ __align__(16) unsigned short lds[2][4][4096];   // 64 KB
    int bh = blockIdx.x;
    int qi = (int)gridDim.y - 1 - blockIdx.y;   // big blocks first
    int tid = threadIdx.x;
    int w = tid >> 6, l = tid & 63;
    int qloc = l & 31, g = l >> 5;
    int q0 = qi * 128;
    int qg = q0 + w * 32 + qloc;

    // Q fragments (pre-scaled 1/8 in qstage); B-frag: col=l&31=q, k=d slice (l>>5)*8
    bf16x8 qf[4];
    {
        const float* qrow = q_s + ((size_t)bh * S_LEN + qg) * HD;
#pragma unroll
        for (int t = 0; t < 4; ++t) {
            float4 u0 = *(const float4*)&qrow[t * 16 + g * 8];
            float4 u1 = *(const float4*)&qrow[t * 16 + g * 8 + 4];
            float vv[8] = {u0.x, u0.y, u0.z, u0.w, u1.x, u1.y, u1.z, u1.w};
            bf16x8 r;
#pragma unroll
            for (int j = 0; j < 8; ++j) r[j] = (short)f2bf(vv[j]);
            qf[t] = r;
        }
    }

    f32x16 o0, o1;
#pragma unroll
    for (int r = 0; r < 16; ++r) { o0[r] = 0.f; o1[r] = 0.f; }
    float m_run = -1e30f, l_run = 0.f;

    int nt = 2 * qi + 2;
    int qwmax = q0 + w * 32 + 31;

    stage_tile(kh, kl, vh, vl, lds[0], w, l, bh, 0);
    __syncthreads();

    for (int t = 0; t < nt; ++t) {
        int kv0 = t * 64;
        int bi = t & 1;
        if (t + 1 < nt)
            stage_tile(kh, kl, vh, vl, lds[bi ^ 1], w, l, bh, (t + 1) * 64);

        if (kv0 <= qwmax) {   // wave-uniform
            const unsigned short* Khp = lds[bi][0];
            const unsigned short* Klp = lds[bi][1];
            const unsigned short* Vhp = lds[bi][2];
            const unsigned short* Vlp = lds[bi][3];

            f32x16 s0, s1;
#pragma unroll
            for (int r = 0; r < 16; ++r) { s0[r] = 0.f; s1[r] = 0.f; }

            // S^T = K * Q^T : A=K rows (keys), B=Q cols (q)
            __builtin_amdgcn_s_setprio(1);
#pragma unroll
            for (int tt = 0; tt < 4; ++tt) {
                int gr = ((2 * tt + g) ^ (qloc & 7)) * 8;
                bf16x8 a0h = *(const bf16x8*)&Khp[qloc * 64 + gr];
                bf16x8 a1h = *(const bf16x8*)&Khp[(32 + qloc) * 64 + gr];
                bf16x8 a0l = *(const bf16x8*)&Klp[qloc * 64 + gr];
                bf16x8 a1l = *(const bf16x8*)&Klp[(32 + qloc) * 64 + gr];
                s0 = MFMA32(a0h, qf[tt], s0);
                s0 = MFMA32(a0l, qf[tt], s0);
                s1 = MFMA32(a1h, qf[tt], s1);
                s1 = MFMA32(a1l, qf[tt], s1);
            }
            __builtin_amdgcn_s_setprio(0);

            // causal mask (diagonal tiles only; wave-uniform gate)
            if (kv0 + 63 > q0 + w * 32) {
#pragma unroll
                for (int r = 0; r < 16; ++r) {
                    int kk = kv0 + QROW(r);
                    if (kk > qg)      s0[r] = -1e30f;
                    if (kk + 32 > qg) s1[r] = -1e30f;
                }
            }

            // online softmax: lane owns q = l&31 across both halves (l, l^32)
            float mx = s0[0];
#pragma unroll
            for (int r = 1; r < 16; ++r) mx = fmaxf(mx, s0[r]);
#pragma unroll
            for (int r = 0; r < 16; ++r) mx = fmaxf(mx, s1[r]);
            mx = fmaxf(mx, __shfl_xor(mx, 32));
            float mnew = fmaxf(m_run, mx);
            float al = __expf(m_run - mnew);
            m_run = mnew;
            float rs = 0.f;
#pragma unroll
            for (int r = 0; r < 16; ++r) { s0[r] = __expf(s0[r] - mnew); rs += s0[r]; }
#pragma unroll
            for (int r = 0; r < 16; ++r) { s1[r] = __expf(s1[r] - mnew); rs += s1[r]; }
            rs += __shfl_xor(rs, 32);
            l_run = l_run * al + rs;
#pragma unroll
            for (int r = 0; r < 16; ++r) {
                float ar = __shfl(al, QROW(r));
                o0[r] *= ar; o1[r] *= ar;
            }

            // P->bf16 A-frags (cvt_pk + permlane32_swap) fused with PV MFMA
            __builtin_amdgcn_s_setprio(1);
#pragma unroll
            for (int ks = 0; ks < 4; ++ks) {
                const int b = (ks & 1) * 8;
                unsigned w0, w1, w2, w3;
                if (ks < 2) {
                    w0 = cvtpk(s0[b + 0], s0[b + 1]);
                    w1 = cvtpk(s0[b + 2], s0[b + 3]);
                    w2 = cvtpk(s0[b + 4], s0[b + 5]);
                    w3 = cvtpk(s0[b + 6], s0[b + 7]);
                } else {
                    w0 = cvtpk(s1[b + 0], s1[b + 1]);
                    w1 = cvtpk(s1[b + 2], s1[b + 3]);
                    w2 = cvtpk(s1[b + 4], s1[b + 5]);
                    w3 = cvtpk(s1[b + 6], s1[b + 7]);
                }
                asm("v_permlane32_swap_b32 %0, %1" : "+v"(w0), "+v"(w2));
                asm("v_permlane32_swap_b32 %0, %1" : "+v"(w1), "+v"(w3));
                U4 u; u.u[0] = w0; u.u[1] = w1; u.u[2] = w2; u.u[3] = w3;
                bf16x8 pa = u.v;
                int gr = ((2 * ks + g) ^ (qloc & 7)) * 8;
                bf16x8 v0h = *(const bf16x8*)&Vhp[qloc * 64 + gr];
                bf16x8 v1h = *(const bf16x8*)&Vhp[(32 + qloc) * 64 + gr];
                bf16x8 v0l = *(const bf16x8*)&Vlp[qloc * 64 + gr];
                bf16x8 v1l = *(const bf16x8*)&Vlp[(32 + qloc) * 64 + gr];
                o0 = MFMA32(pa, v0h, o0);
                o0 = MFMA32(pa, v0l, o0);
                o1 = MFMA32(pa, v1h, o1);
                o1 = MFMA32(pa, v1l, o1);
            }
            __builtin_amdgcn_s_setprio(0);
        }
        __syncthreads();
    }

    int bb = bh >> 4, h = bh & 15;
#pragma unroll
    for (int r = 0; r < 16; ++r) {
        float li = __shfl(l_run, QROW(r));
        float inv = 1.f / li;
        int qq = q0 + w * 32 + QROW(r);
        size_t base = ((size_t)(bb * S_LEN + qq)) * D_DIM + h * HD + qloc;
        a_s[base]      = o0[r] * inv;
        a_s[base + 32] = o1[r] * inv;
    }
}

// ---------------- K3 fallback: f32 flash attention (round-1) ----------------
#define LSTR 68
__global__ __launch_bounds__(256) void attn_kernel(const float* __restrict__ q_s,
    const float* __restrict__ k_s, const float* __restrict__ v_s,
    float* __restrict__ a_s) {
    __shared__ float Qt[64][LSTR];
    __shared__ float KP[64][LSTR];
    __shared__ float Vs[64][LSTR];
    int bh = blockIdx.x;
    int qi = 31 - blockIdx.y;
    int tid = threadIdx.x;
    int tx = tid & 15, ty = tid >> 4;

#pragma unroll
    for (int qq = 0; qq < 4; ++qq) {
        int q  = qq * 16 + (tid >> 4);
        int d4 = (tid & 15) * 4;
        float4 v = *(const float4*)&q_s[((size_t)bh * S_LEN + qi * 64 + q) * HD + d4];
        Qt[d4 + 0][q] = v.x; Qt[d4 + 1][q] = v.y;
        Qt[d4 + 2][q] = v.z; Qt[d4 + 3][q] = v.w;
    }

    float o[4][4];
#pragma unroll
    for (int r = 0; r < 4; ++r)
#pragma unroll
        for (int c = 0; c < 4; ++c) o[r][c] = 0.f;
    float mrow[4] = {-1e30f, -1e30f, -1e30f, -1e30f};
    float lrow[4] = {0.f, 0.f, 0.f, 0.f};

    for (int kt = 0; kt <= qi; ++kt) {
        __syncthreads();
#pragma unroll
        for (int kk2 = 0; kk2 < 4; ++kk2) {
            int k  = kk2 * 16 + (tid >> 4);
            int d4 = (tid & 15) * 4;
            size_t rowoff = ((size_t)bh * S_LEN + kt * 64 + k) * HD + d4;
            float4 kv4 = *(const float4*)&k_s[rowoff];
            KP[d4 + 0][k] = kv4.x; KP[d4 + 1][k] = kv4.y;
            KP[d4 + 2][k] = kv4.z; KP[d4 + 3][k] = kv4.w;
            float4 vv4 = *(const float4*)&v_s[rowoff];
            *(float4*)&Vs[k][d4] = vv4;
        }
        __syncthreads();

        float s[4][4];
#pragma unroll
        for (int r = 0; r < 4; ++r)
#pragma unroll
            for (int c = 0; c < 4; ++c) s[r][c] = 0.f;
#pragma unroll 8
        for (int d = 0; d < 64; ++d) {
            float4 qv = *(const float4*)&Qt[d][ty * 4];
            float4 kv = *(const float4*)&KP[d][tx * 4];
            float qa[4] = {qv.x, qv.y, qv.z, qv.w};
            float ka[4] = {kv.x, kv.y, kv.z, kv.w};
#pragma unroll
            for (int r = 0; r < 4; ++r)
#pragma unroll
                for (int c = 0; c < 4; ++c)
                    s[r][c] = fmaf(qa[r], ka[c], s[r][c]);
        }
        if (kt == qi) {
#pragma unroll
            for (int r = 0; r < 4; ++r)
#pragma unroll
                for (int c = 0; c < 4; ++c)
                    if (tx * 4 + c > ty * 4 + r) s[r][c] = -1e30f;
        }
        __syncthreads();

        float p[4][4];
#pragma unroll
        for (int r = 0; r < 4; ++r) {
            float mx = fmaxf(fmaxf(s[r][0], s[r][1]), fmaxf(s[r][2], s[r][3]));
            mx = fmaxf(mx, __shfl_xor(mx, 1));
            mx = fmaxf(mx, __shfl_xor(mx, 2));
            mx = fmaxf(mx, __shfl_xor(mx, 4));
            mx = fmaxf(mx, __shfl_xor(mx, 8));
            float mn = fmaxf(mrow[r], mx);
            float alpha = __expf(mrow[r] - mn);
            mrow[r] = mn;
            float rsum = 0.f;
#pragma unroll
            for (int c = 0; c < 4; ++c) {
                p[r][c] = __expf(s[r][c] - mn);
                rsum += p[r][c];
            }
            rsum += __shfl_xor(rsum, 1);
            rsum += __shfl_xor(rsum, 2);
            rsum += __shfl_xor(rsum, 4);
            rsum += __shfl_xor(rsum, 8);
            lrow[r] = lrow[r] * alpha + rsum;
#pragma unroll
            for (int c = 0; c < 4; ++c) o[r][c] *= alpha;
            *(float4*)&KP[ty * 4 + r][tx * 4] =
                make_float4(p[r][0], p[r][1], p[r][2], p[r][3]);
        }
        __syncthreads();

#pragma unroll 8
        for (int k = 0; k < 64; ++k) {
            float4 vv = *(const float4*)&Vs[k][tx * 4];
            float va[4] = {vv.x, vv.y, vv.z, vv.w};
#pragma unroll
            for (int r = 0; r < 4; ++r) {
                float pr = KP[ty * 4 + r][k];
#pragma unroll
                for (int c = 0; c < 4; ++c)
                    o[r][c] = fmaf(pr, va[c], o[r][c]);
            }
        }
    }

    int b = bh >> 4, h = bh & 15;
#pragma unroll
    for (int r = 0; r < 4; ++r) {
        int i = qi * 64 + ty * 4 + r;
        float inv = 1.f / lrow[r];
        *(float4*)&a_s[((size_t)(b * S_LEN + i)) * D_DIM + h * HD + tx * 4] =
            make_float4(o[r][0] * inv, o[r][1] * inv, o[r][2] * inv, o[r][3] * inv);
    }
}

// ------ K2 fallback (old fp32 path, used only if ws_size is too small) ------
__global__ __launch_bounds__(256) void qkv_kernel(const float* __restrict__ x,
    const float* __restrict__ w, const float* __restrict__ bias,
    const float* __restrict__ qa2, const float* __restrict__ va2,
    const float* __restrict__ tq, const float* __restrict__ tv,
    float* __restrict__ qstage, float* __restrict__ pres) {
    __shared__ float As[128][17];
    __shared__ float Bs[16][64];
    int bx = blockIdx.x;
    int by = blockIdx.y;
    int tid = threadIdx.x;
    int tx = tid & 15, ty = tid >> 4;

    float c[8][4];
#pragma unroll
    for (int i = 0; i < 8; ++i)
#pragma unroll
        for (int j = 0; j < 4; ++j) c[i][j] = 0.f;

    for (int k0 = 0; k0 < D_DIM; k0 += 16) {
#pragma unroll
        for (int u = 0; u < 2; ++u) {
            int f4 = tid + 256 * u;
            int row = f4 >> 2;
            int kk4 = (f4 & 3) * 4;
            float4 av = *(const float4*)&x[(size_t)(by * 128 + row) * D_DIM + k0 + kk4];
            As[row][kk4 + 0] = av.x; As[row][kk4 + 1] = av.y;
            As[row][kk4 + 2] = av.z; As[row][kk4 + 3] = av.w;
        }
        {
            int kkb = tid >> 4;
            int col4 = (tid & 15) * 4;
            *(float4*)&Bs[kkb][col4] =
                *(const float4*)&w[(size_t)(k0 + kkb) * N3 + bx * 64 + col4];
        }
        __syncthreads();
#pragma unroll
        for (int kk = 0; kk < 16; ++kk) {
            float4 bv = *(const float4*)&Bs[kk][tx * 4];
#pragma unroll
            for (int i = 0; i < 8; ++i) {
                float a = As[ty * 8 + i][kk];
                c[i][0] = fmaf(a, bv.x, c[i][0]);
                c[i][1] = fmaf(a, bv.y, c[i][1]);
                c[i][2] = fmaf(a, bv.z, c[i][2]);
                c[i][3] = fmaf(a, bv.w, c[i][3]);
            }
        }
        __syncthreads();
    }

    int seg = bx >> 4;
    int h = bx & 15;
    int ncol = bx * 64 + tx * 4;
    float4 bias4 = *(const float4*)&bias[ncol];
    int nloc = h * 64 + tx * 4;

    float4 arr[16];
    if (seg != 1) {
        const float* a2 = (seg == 0 ? qa2 : va2);
#pragma unroll
        for (int jj = 0; jj < 16; ++jj)
            arr[jj] = *(const float4*)&a2[jj * D_DIM + nloc];
    }

#pragma unroll
    for (int i = 0; i < 8; ++i) {
        int t = by * 128 + ty * 8 + i;
        float v0 = c[i][0] + bias4.x;
        float v1 = c[i][1] + bias4.y;
        float v2 = c[i][2] + bias4.z;
        float v3 = c[i][3] + bias4.w;
        if (seg != 1) {
            const float* trow = (seg == 0 ? tq : tv) + t * 16;
            float l0 = 0.f, l1 = 0.f, l2 = 0.f, l3 = 0.f;
#pragma unroll
            for (int jj = 0; jj < 16; ++jj) {
                float tvv = trow[jj];
                l0 = fmaf(tvv, arr[jj].x, l0);
                l1 = fmaf(tvv, arr[jj].y, l1);
                l2 = fmaf(tvv, arr[jj].z, l2);
                l3 = fmaf(tvv, arr[jj].w, l3);
            }
            v0 += 0.5f * l0; v1 += 0.5f * l1; v2 += 0.5f * l2; v3 += 0.5f * l3;
        }
        int b = t >> 11, sidx = t & 2047;
        size_t idx = (((size_t)(b * NH + h) * S_LEN + sidx) * HD) + tx * 4;
        if (seg == 0) {
            *(float4*)&qstage[idx] = make_float4(v0 * 0.125f, v1 * 0.125f,
                                                 v2 * 0.125f, v3 * 0.125f);
        } else if (seg == 1) {
            *(float4*)&pres[idx] = make_float4(v0, v1, v2, v3);
        } else {
            *(float4*)&pres[OUT_KV_ELEMS + idx] = make_float4(v0, v1, v2, v3);
        }
    }
}

// ---------------- K4: out = a_s @ c_proj_w + c_proj_b  -> f32 ----------------
__global__ __launch_bounds__(256) void proj_kernel(const float* __restrict__ A,
    const float* __restrict__ w, const float* __restrict__ bias,
    float* __restrict__ outp) {
    __shared__ float As[128][17];
    __shared__ float Bs[16][64];
    int bx = blockIdx.x;
    int by = blockIdx.y;
    int tid = threadIdx.x;
    int tx = tid & 15, ty = tid >> 4;

    float c[8][4];
#pragma unroll
    for (int i = 0; i < 8; ++i)
#pragma unroll
        for (int j = 0; j < 4; ++j) c[i][j] = 0.f;

    for (int k0 = 0; k0 < D_DIM; k0 += 16) {
#pragma unroll
        for (int u = 0; u < 2; ++u) {
            int f4 = tid + 256 * u;
            int row = f4 >> 2;
            int kk4 = (f4 & 3) * 4;
            float4 av = *(const float4*)&A[(size_t)(by * 128 + row) * D_DIM + k0 + kk4];
            As[row][kk4 + 0] = av.x; As[row][kk4 + 1] = av.y;
            As[row][kk4 + 2] = av.z; As[row][kk4 + 3] = av.w;
        }
        {
            int kkb = tid >> 4;
            int col4 = (tid & 15) * 4;
            *(float4*)&Bs[kkb][col4] =
                *(const float4*)&w[(size_t)(k0 + kkb) * D_DIM + bx * 64 + col4];
        }
        __syncthreads();
#pragma unroll
        for (int kk = 0; kk < 16; ++kk) {
            float4 bv = *(const float4*)&Bs[kk][tx * 4];
#pragma unroll
            for (int i = 0; i < 8; ++i) {
                float a = As[ty * 8 + i][kk];
                c[i][0] = fmaf(a, bv.x, c[i][0]);
                c[i][1] = fmaf(a, bv.y, c[i][1]);
                c[i][2] = fmaf(a, bv.z, c[i][2]);
                c[i][3] = fmaf(a, bv.w, c[i][3]);
            }
        }
        __syncthreads();
    }

    int ncol = bx * 64 + tx * 4;
    float4 bias4 = *(const float4*)&bias[ncol];
#pragma unroll
    for (int i = 0; i < 8; ++i) {
        int t = by * 128 + ty * 8 + i;
        *(float4*)&outp[(size_t)t * D_DIM + ncol] =
            make_float4(c[i][0] + bias4.x, c[i][1] + bias4.y,
                        c[i][2] + bias4.z, c[i][3] + bias4.w);
    }
}

extern "C" void kernel_launch(void* const* d_in, const int* in_sizes, int n_in,
                              void* d_out, int out_size, void* d_ws, size_t ws_size,
                              hipStream_t stream) {
    const float* x        = (const float*)d_in[0];
    const float* c_attn_w = (const float*)d_in[1];
    const float* c_attn_b = (const float*)d_in[2];
    const float* c_proj_w = (const float*)d_in[3];
    const float* c_proj_b = (const float*)d_in[4];
    const float* q_a1     = (const float*)d_in[5];
    const float* q_a2     = (const float*)d_in[6];
    const float* v_a1     = (const float*)d_in[7];
    const float* v_a2     = (const float*)d_in[8];

    float* outf   = (float*)d_out;
    float* qstage = outf;                  // a-region reused as f32 q staging [B,H,S,hd]
    float* pres   = outf + OUT_A_ELEMS;    // present [2,B,H,S,hd] f32

    // workspace layout:
    //  phase A (pre-qkv):  tq[0,256K) tv[256K,512K) wt_hi/lo[512K,13.5M) a_hi/lo[13.5M,30.8M)
    //  phase B (post-qkv): kp_h[0,8M) kp_l[8M,16M) vt_h[16M,24M) vt_l[24M,32M)   (reuses phase A)
    //  a_s:                [32M, 48M)
    char* wsb = (char*)d_ws;
    float* tq = (float*)wsb;
    float* tv = (float*)(wsb + 262144);
    unsigned short* wt_hi = (unsigned short*)(wsb + 524288);
    unsigned short* wt_lo = (unsigned short*)(wsb + 524288 + 6488064);
    unsigned short* a_hi  = (unsigned short*)(wsb + 13500416);
    unsigned short* a_lo  = (unsigned short*)(wsb + 13500416 + 8650752);
    unsigned short* kp_h  = (unsigned short*)wsb;
    unsigned short* kp_l  = (unsigned short*)(wsb + 8388608);
    unsigned short* vt_h  = (unsigned short*)(wsb + 16777216);
    unsigned short* vt_l  = (unsigned short*)(wsb + 25165824);
    float* a_sn = (float*)(wsb + 33554432);
    const size_t WS_FULL = 50331648;       // full MFMA pipeline
    const size_t WS_MID  = 30801920;       // round-1 pipeline (MFMA qkv, f32 attn)

    lora1_kernel<<<dim3(T_TOK), dim3(64), 0, stream>>>(x, q_a1, v_a1, tq, tv);

    if (ws_size >= WS_FULL) {
        splitA_kernel<<<dim3((T_TOK * (KAUG / 4) + 255) / 256), dim3(256), 0, stream>>>(
            x, tq, tv, a_hi, a_lo);
        splitW_kernel<<<dim3(48, KAUG / 32), dim3(256), 0, stream>>>(
            c_attn_w, q_a2, v_a2, wt_hi, wt_lo);
        qkv_mfma<<<dim3(24, 32), dim3(256), 0, stream>>>(
            a_hi, a_lo, wt_hi, wt_lo, c_attn_b, qstage, pres);
        kprep_kernel<<<dim3(2048), dim3(256), 0, stream>>>(pres, kp_h, kp_l);
        vtprep_kernel<<<dim3(32, 32), dim3(256), 0, stream>>>(
            pres + OUT_KV_ELEMS, vt_h, vt_l);
        attn_mfma<<<dim3(32, 16), dim3(256), 0, stream>>>(
            qstage, kp_h, kp_l, vt_h, vt_l, a_sn);
        proj_kernel<<<dim3(16, 32), dim3(256), 0, stream>>>(
            a_sn, c_proj_w, c_proj_b, outf);
    } else if (ws_size >= WS_MID) {
        float* a_s = (float*)(wsb + 13500416);   // aliases dead a_hi/a_lo
        splitA_kernel<<<dim3((T_TOK * (KAUG / 4) + 255) / 256), dim3(256), 0, stream>>>(
            x, tq, tv, a_hi, a_lo);
        splitW_kernel<<<dim3(48, KAUG / 32), dim3(256), 0, stream>>>(
            c_attn_w, q_a2, v_a2, wt_hi, wt_lo);
        qkv_mfma<<<dim3(24, 32), dim3(256), 0, stream>>>(
            a_hi, a_lo, wt_hi, wt_lo, c_attn_b, qstage, pres);
        attn_kernel<<<dim3(32, 32), dim3(256), 0, stream>>>(
            qstage, pres, pres + OUT_KV_ELEMS, a_s);
        proj_kernel<<<dim3(16, 32), dim3(256), 0, stream>>>(
            a_s, c_proj_w, c_proj_b, outf);
    } else {
        float* a_s2 = tv + 65536;
        qkv_kernel<<<dim3(48, 32), dim3(256), 0, stream>>>(x, c_attn_w, c_attn_b,
            q_a2, v_a2, tq, tv, qstage, pres);
        attn_kernel<<<dim3(32, 32), dim3(256), 0, stream>>>(
            qstage, pres, pres + OUT_KV_ELEMS, a_s2);
        proj_kernel<<<dim3(16, 32), dim3(256), 0, stream>>>(
            a_s2, c_proj_w, c_proj_b, outf);
    }
}

// Round 3
// 365.465 us; speedup vs baseline: 2.7929x; 1.4850x over previous
//
#include <hip/hip_runtime.h>

#define T_TOK 4096   // B*S
#define D_DIM 1024
#define N3    3072
#define S_LEN 2048
#define NH    16
#define HD    64
#define KAUG  1056   // 1024 + 16 (q-lora) + 16 (v-lora)

#define OUT_A_ELEMS   4194304   // B*S*D   (f32 elements)
#define OUT_KV_ELEMS  4194304   // B*H*S*hd

typedef __attribute__((ext_vector_type(8))) short bf16x8;
typedef __attribute__((ext_vector_type(4))) float f32x4;
typedef __attribute__((ext_vector_type(16))) float f32x16;

union U4 { unsigned u[4]; bf16x8 v; };

__device__ __forceinline__ unsigned short f2bf(float f) {
    unsigned u = __float_as_uint(f);
    u += 0x7FFFu + ((u >> 16) & 1u);
    return (unsigned short)(u >> 16);
}
__device__ __forceinline__ float bf2f(unsigned short h) {
    return __uint_as_float(((unsigned)h) << 16);
}
__device__ __forceinline__ unsigned cvtpk(float a, float b) {
    unsigned r;
    asm("v_cvt_pk_bf16_f32 %0, %1, %2" : "=v"(r) : "v"(a), "v"(b));
    return r;
}

#define GLL16(gp, lp) __builtin_amdgcn_global_load_lds( \
    (const __attribute__((address_space(1))) unsigned int*)(gp), \
    (__attribute__((address_space(3))) unsigned int*)(lp), 16, 0, 0)

#define MFMA32(A, B, C) __builtin_amdgcn_mfma_f32_32x32x16_bf16(A, B, C, 0, 0, 0)

// ---------------- K1 (v2): lora down-proj  tq = x@q_a1, tv = x@v_a1 ----------------
// One token per wave. lane = cg(0..7: 4 cols each; cg<4 -> q, else v) + 8*ks(0..7).
// 4 independent accumulators per lane; shfl_xor reduce over k-slices.
__global__ __launch_bounds__(256) void lora1_v2(const float* __restrict__ x,
    const float* __restrict__ qa1, const float* __restrict__ va1,
    float* __restrict__ tq, float* __restrict__ tv) {
    int tid = threadIdx.x;
    int w = tid >> 6;
    int lane = tid & 63;
    int t = blockIdx.x * 4 + w;
    int cg = lane & 7;
    int ks = lane >> 3;
    const float* a1 = (cg < 4) ? qa1 : va1;
    int c4 = (cg & 3) * 4;
    const float* xr = x + (size_t)t * D_DIM + ks * 128;
    const float* ar = a1 + (size_t)(ks * 128) * 16 + c4;
    float4 acc = make_float4(0.f, 0.f, 0.f, 0.f);
#pragma unroll 8
    for (int j = 0; j < 128; ++j) {
        float xv = xr[j];
        float4 av = *(const float4*)&ar[j * 16];
        acc.x = fmaf(xv, av.x, acc.x);
        acc.y = fmaf(xv, av.y, acc.y);
        acc.z = fmaf(xv, av.z, acc.z);
        acc.w = fmaf(xv, av.w, acc.w);
    }
#pragma unroll
    for (int m = 8; m < 64; m <<= 1) {
        acc.x += __shfl_xor(acc.x, m);
        acc.y += __shfl_xor(acc.y, m);
        acc.z += __shfl_xor(acc.z, m);
        acc.w += __shfl_xor(acc.w, m);
    }
    if (lane < 8) {
        float* dst = (cg < 4) ? &tq[t * 16 + c4] : &tv[t * 16 + (cg - 4) * 4];
        *(float4*)dst = acc;
    }
}

// ---------------- prep: split A_aug = [x | tq | tv] into bf16 hi/lo planes [T_TOK][KAUG]
__global__ __launch_bounds__(256) void splitA_kernel(const float* __restrict__ x,
    const float* __restrict__ tq, const float* __restrict__ tv,
    unsigned short* __restrict__ ah, unsigned short* __restrict__ al) {
    int idx = blockIdx.x * 256 + threadIdx.x;
    const int total = T_TOK * (KAUG / 4);
    if (idx >= total) return;
    int t = idx / (KAUG / 4);
    int c4 = (idx - t * (KAUG / 4)) * 4;
    float4 v;
    if (c4 < D_DIM)           v = *(const float4*)&x[(size_t)t * D_DIM + c4];
    else if (c4 < D_DIM + 16) v = *(const float4*)&tq[t * 16 + (c4 - D_DIM)];
    else                      v = *(const float4*)&tv[t * 16 + (c4 - D_DIM - 16)];
    ushort4 h, l;
    h.x = f2bf(v.x); l.x = f2bf(v.x - bf2f(h.x));
    h.y = f2bf(v.y); l.y = f2bf(v.y - bf2f(h.y));
    h.z = f2bf(v.z); l.z = f2bf(v.z - bf2f(h.z));
    h.w = f2bf(v.w); l.w = f2bf(v.w - bf2f(h.w));
    *(ushort4*)&ah[(size_t)t * KAUG + c4] = h;
    *(ushort4*)&al[(size_t)t * KAUG + c4] = l;
}

// ---------------- prep: W_aug^T split planes [N3][KAUG]
__global__ __launch_bounds__(256) void splitW_kernel(const float* __restrict__ w,
    const float* __restrict__ qa2, const float* __restrict__ va2,
    unsigned short* __restrict__ bh, unsigned short* __restrict__ bl) {
    __shared__ float T[32][65];
    int bn = blockIdx.x;
    int bk = blockIdx.y;
    int tid = threadIdx.x;
#pragma unroll
    for (int u = 0; u < 2; ++u) {
        int id = tid + 256 * u;
        int kr = id >> 4;
        int n4 = (id & 15) * 4;
        int k = bk * 32 + kr;
        int n = bn * 64 + n4;
        float4 v = make_float4(0.f, 0.f, 0.f, 0.f);
        if (k < D_DIM) {
            v = *(const float4*)&w[(size_t)k * N3 + n];
        } else if (k < D_DIM + 16) {
            if (n < D_DIM) {
                float4 q4 = *(const float4*)&qa2[(k - D_DIM) * D_DIM + n];
                v = make_float4(q4.x * 0.5f, q4.y * 0.5f, q4.z * 0.5f, q4.w * 0.5f);
            }
        } else {
            if (n >= 2 * D_DIM) {
                float4 q4 = *(const float4*)&va2[(k - D_DIM - 16) * D_DIM + (n - 2 * D_DIM)];
                v = make_float4(q4.x * 0.5f, q4.y * 0.5f, q4.z * 0.5f, q4.w * 0.5f);
            }
        }
        T[kr][n4 + 0] = v.x; T[kr][n4 + 1] = v.y;
        T[kr][n4 + 2] = v.z; T[kr][n4 + 3] = v.w;
    }
    __syncthreads();
    int n = tid >> 2;
    int k8 = (tid & 3) * 8;
    unsigned short hh[8], ll[8];
#pragma unroll
    for (int j = 0; j < 8; ++j) {
        float v = T[k8 + j][n];
        hh[j] = f2bf(v);
        ll[j] = f2bf(v - bf2f(hh[j]));
    }
    size_t ro = (size_t)(bn * 64 + n) * KAUG + bk * 32 + k8;
    ushort4 h0, h1, l0, l1;
    h0.x = hh[0]; h0.y = hh[1]; h0.z = hh[2]; h0.w = hh[3];
    h1.x = hh[4]; h1.y = hh[5]; h1.z = hh[6]; h1.w = hh[7];
    l0.x = ll[0]; l0.y = ll[1]; l0.z = ll[2]; l0.w = ll[3];
    l1.x = ll[4]; l1.y = ll[5]; l1.z = ll[6]; l1.w = ll[7];
    *(ushort4*)&bh[ro]     = h0;
    *(ushort4*)&bh[ro + 4] = h1;
    *(ushort4*)&bl[ro]     = l0;
    *(ushort4*)&bl[ro + 4] = l1;
}

// ---------------- prep: c_proj_w -> transposed split planes [n][k] = [1024][1024]
__global__ __launch_bounds__(256) void wprep_kernel(const float* __restrict__ w,
    unsigned short* __restrict__ bh, unsigned short* __restrict__ bl) {
    __shared__ float T[32][65];
    int bn = blockIdx.x;   // 0..15 (64 n)
    int bk = blockIdx.y;   // 0..31 (32 k)
    int tid = threadIdx.x;
#pragma unroll
    for (int u = 0; u < 2; ++u) {
        int id = tid + 256 * u;
        int kr = id >> 4;
        int n4 = (id & 15) * 4;
        float4 v = *(const float4*)&w[(size_t)(bk * 32 + kr) * D_DIM + bn * 64 + n4];
        T[kr][n4 + 0] = v.x; T[kr][n4 + 1] = v.y;
        T[kr][n4 + 2] = v.z; T[kr][n4 + 3] = v.w;
    }
    __syncthreads();
    int n = tid >> 2;
    int k8 = (tid & 3) * 8;
    unsigned short hh[8], ll[8];
#pragma unroll
    for (int j = 0; j < 8; ++j) {
        float v = T[k8 + j][n];
        hh[j] = f2bf(v);
        ll[j] = f2bf(v - bf2f(hh[j]));
    }
    size_t ro = (size_t)(bn * 64 + n) * D_DIM + bk * 32 + k8;
    ushort4 h0, h1, l0, l1;
    h0.x = hh[0]; h0.y = hh[1]; h0.z = hh[2]; h0.w = hh[3];
    h1.x = hh[4]; h1.y = hh[5]; h1.z = hh[6]; h1.w = hh[7];
    l0.x = ll[0]; l0.y = ll[1]; l0.z = ll[2]; l0.w = ll[3];
    l1.x = ll[4]; l1.y = ll[5]; l1.z = ll[6]; l1.w = ll[7];
    *(ushort4*)&bh[ro]     = h0;
    *(ushort4*)&bh[ro + 4] = h1;
    *(ushort4*)&bl[ro]     = l0;
    *(ushort4*)&bl[ro + 4] = l1;
}

// ---------------- K2: split-bf16 MFMA GEMM, lora folded into K, fused scatter
__global__ __launch_bounds__(256) void qkv_mfma(
    const unsigned short* __restrict__ ah_g, const unsigned short* __restrict__ al_g,
    const unsigned short* __restrict__ bh_g, const unsigned short* __restrict__ bl_g,
    const float* __restrict__ bias,
    float* __restrict__ qstage, float* __restrict__ pres) {
    __shared__ unsigned short Ah[128 * 32], Al[128 * 32], Bh[128 * 32], Bl[128 * 32];
    int bn = blockIdx.x;
    int bm = blockIdx.y;
    int tid = threadIdx.x;
    int w = tid >> 6, l = tid & 63;
    int wr = w >> 1, wc = w & 1;

    f32x4 acc[4][4];
#pragma unroll
    for (int i = 0; i < 4; ++i)
#pragma unroll
        for (int j = 0; j < 4; ++j)
            acc[i][j] = (f32x4){0.f, 0.f, 0.f, 0.f};

    int srow = l >> 2;
    int sk = (l & 3) * 8;
    const size_t a_base0 = (size_t)(bm * 128 + w * 32 + srow) * KAUG + sk;
    const size_t a_base1 = a_base0 + (size_t)16 * KAUG;
    const size_t b_base0 = (size_t)(bn * 128 + w * 32 + srow) * KAUG + sk;
    const size_t b_base1 = b_base0 + (size_t)16 * KAUG;
    unsigned short* pAh0 = &Ah[(w * 32) * 32];
    unsigned short* pAh1 = &Ah[(w * 32 + 16) * 32];
    unsigned short* pAl0 = &Al[(w * 32) * 32];
    unsigned short* pAl1 = &Al[(w * 32 + 16) * 32];
    unsigned short* pBh0 = &Bh[(w * 32) * 32];
    unsigned short* pBh1 = &Bh[(w * 32 + 16) * 32];
    unsigned short* pBl0 = &Bl[(w * 32) * 32];
    unsigned short* pBl1 = &Bl[(w * 32 + 16) * 32];

    int lrow = l & 15;
    int lq = (l >> 4) * 8;

    for (int k0 = 0; k0 < KAUG; k0 += 32) {
        __syncthreads();
        GLL16(ah_g + a_base0 + k0, pAh0);
        GLL16(ah_g + a_base1 + k0, pAh1);
        GLL16(al_g + a_base0 + k0, pAl0);
        GLL16(al_g + a_base1 + k0, pAl1);
        GLL16(bh_g + b_base0 + k0, pBh0);
        GLL16(bh_g + b_base1 + k0, pBh1);
        GLL16(bl_g + b_base0 + k0, pBl0);
        GLL16(bl_g + b_base1 + k0, pBl1);
        __syncthreads();

        bf16x8 fa_h[4], fa_l[4], fb_h[4], fb_l[4];
#pragma unroll
        for (int i = 0; i < 4; ++i) {
            int ro = (wr * 64 + i * 16 + lrow) * 32 + lq;
            fa_h[i] = *(const bf16x8*)&Ah[ro];
            fa_l[i] = *(const bf16x8*)&Al[ro];
        }
#pragma unroll
        for (int j = 0; j < 4; ++j) {
            int ro = (wc * 64 + j * 16 + lrow) * 32 + lq;
            fb_h[j] = *(const bf16x8*)&Bh[ro];
            fb_l[j] = *(const bf16x8*)&Bl[ro];
        }
#pragma unroll
        for (int i = 0; i < 4; ++i)
#pragma unroll
            for (int j = 0; j < 4; ++j) {
                acc[i][j] = __builtin_amdgcn_mfma_f32_16x16x32_bf16(
                    fa_h[i], fb_h[j], acc[i][j], 0, 0, 0);
                acc[i][j] = __builtin_amdgcn_mfma_f32_16x16x32_bf16(
                    fa_h[i], fb_l[j], acc[i][j], 0, 0, 0);
                acc[i][j] = __builtin_amdgcn_mfma_f32_16x16x32_bf16(
                    fa_l[i], fb_h[j], acc[i][j], 0, 0, 0);
            }
    }

    int seg = bn >> 3;
#pragma unroll
    for (int j = 0; j < 4; ++j) {
        int n = bn * 128 + wc * 64 + j * 16 + lrow;
        float bz = bias[n];
        int h = (n >> 6) & 15;
        int d = n & 63;
#pragma unroll
        for (int i = 0; i < 4; ++i) {
            int tbase = bm * 128 + wr * 64 + i * 16 + (l >> 4) * 4;
#pragma unroll
            for (int r = 0; r < 4; ++r) {
                int t = tbase + r;
                float v = acc[i][j][r] + bz;
                int bb = t >> 11, s = t & 2047;
                size_t idx = (((size_t)(bb * NH + h) * S_LEN + s) * HD) + d;
                if (seg == 0)      qstage[idx] = v * 0.125f;
                else if (seg == 1) pres[idx] = v;
                else               pres[OUT_KV_ELEMS + idx] = v;
            }
        }
    }
}

// ---------------- K5: proj = a @ c_proj_w + b via split-bf16 MFMA ----------------
__global__ __launch_bounds__(256) void proj_mfma(
    const unsigned short* __restrict__ ah_g, const unsigned short* __restrict__ al_g,
    const unsigned short* __restrict__ bh_g, const unsigned short* __restrict__ bl_g,
    const float* __restrict__ bias, float* __restrict__ outp) {
    __shared__ unsigned short Ah[128 * 32], Al[128 * 32], Bh[128 * 32], Bl[128 * 32];
    int bn = blockIdx.x;   // 0..7
    int bm = blockIdx.y;   // 0..31
    int tid = threadIdx.x;
    int w = tid >> 6, l = tid & 63;
    int wr = w >> 1, wc = w & 1;

    f32x4 acc[4][4];
#pragma unroll
    for (int i = 0; i < 4; ++i)
#pragma unroll
        for (int j = 0; j < 4; ++j)
            acc[i][j] = (f32x4){0.f, 0.f, 0.f, 0.f};

    int srow = l >> 2;
    int sk = (l & 3) * 8;
    const size_t a_base0 = (size_t)(bm * 128 + w * 32 + srow) * D_DIM + sk;
    const size_t a_base1 = a_base0 + (size_t)16 * D_DIM;
    const size_t b_base0 = (size_t)(bn * 128 + w * 32 + srow) * D_DIM + sk;
    const size_t b_base1 = b_base0 + (size_t)16 * D_DIM;
    unsigned short* pAh0 = &Ah[(w * 32) * 32];
    unsigned short* pAh1 = &Ah[(w * 32 + 16) * 32];
    unsigned short* pAl0 = &Al[(w * 32) * 32];
    unsigned short* pAl1 = &Al[(w * 32 + 16) * 32];
    unsigned short* pBh0 = &Bh[(w * 32) * 32];
    unsigned short* pBh1 = &Bh[(w * 32 + 16) * 32];
    unsigned short* pBl0 = &Bl[(w * 32) * 32];
    unsigned short* pBl1 = &Bl[(w * 32 + 16) * 32];

    int lrow = l & 15;
    int lq = (l >> 4) * 8;

    for (int k0 = 0; k0 < D_DIM; k0 += 32) {
        __syncthreads();
        GLL16(ah_g + a_base0 + k0, pAh0);
        GLL16(ah_g + a_base1 + k0, pAh1);
        GLL16(al_g + a_base0 + k0, pAl0);
        GLL16(al_g + a_base1 + k0, pAl1);
        GLL16(bh_g + b_base0 + k0, pBh0);
        GLL16(bh_g + b_base1 + k0, pBh1);
        GLL16(bl_g + b_base0 + k0, pBl0);
        GLL16(bl_g + b_base1 + k0, pBl1);
        __syncthreads();

        bf16x8 fa_h[4], fa_l[4], fb_h[4], fb_l[4];
#pragma unroll
        for (int i = 0; i < 4; ++i) {
            int ro = (wr * 64 + i * 16 + lrow) * 32 + lq;
            fa_h[i] = *(const bf16x8*)&Ah[ro];
            fa_l[i] = *(const bf16x8*)&Al[ro];
        }
#pragma unroll
        for (int j = 0; j < 4; ++j) {
            int ro = (wc * 64 + j * 16 + lrow) * 32 + lq;
            fb_h[j] = *(const bf16x8*)&Bh[ro];
            fb_l[j] = *(const bf16x8*)&Bl[ro];
        }
#pragma unroll
        for (int i = 0; i < 4; ++i)
#pragma unroll
            for (int j = 0; j < 4; ++j) {
                acc[i][j] = __builtin_amdgcn_mfma_f32_16x16x32_bf16(
                    fa_h[i], fb_h[j], acc[i][j], 0, 0, 0);
                acc[i][j] = __builtin_amdgcn_mfma_f32_16x16x32_bf16(
                    fa_h[i], fb_l[j], acc[i][j], 0, 0, 0);
                acc[i][j] = __builtin_amdgcn_mfma_f32_16x16x32_bf16(
                    fa_l[i], fb_h[j], acc[i][j], 0, 0, 0);
            }
    }

#pragma unroll
    for (int j = 0; j < 4; ++j) {
        int n = bn * 128 + wc * 64 + j * 16 + lrow;
        float bz = bias[n];
#pragma unroll
        for (int i = 0; i < 4; ++i) {
            int tbase = bm * 128 + wr * 64 + i * 16 + (l >> 4) * 4;
#pragma unroll
            for (int r = 0; r < 4; ++r)
                outp[(size_t)(tbase + r) * D_DIM + n] = acc[i][j][r] + bz;
        }
    }
}

// ---------------- prep: K rows -> swizzled bf16 hi/lo planes [bh][key][64]
__global__ __launch_bounds__(256) void kprep_kernel(const float* __restrict__ kin,
    unsigned short* __restrict__ khp, unsigned short* __restrict__ klp) {
    int id = blockIdx.x * 256 + threadIdx.x;
    int rowi = id >> 3;
    int gsrc = id & 7;
    const float* src = kin + (size_t)rowi * 64 + gsrc * 8;
    float4 v0 = *(const float4*)src;
    float4 v1 = *(const float4*)(src + 4);
    int key = rowi & 2047;
    int gp = gsrc ^ (key & 7);
    size_t dst = (size_t)rowi * 64 + gp * 8;
    float vv[8] = {v0.x, v0.y, v0.z, v0.w, v1.x, v1.y, v1.z, v1.w};
    bf16x8 h, lo;
#pragma unroll
    for (int j = 0; j < 8; ++j) {
        unsigned short hh = f2bf(vv[j]);
        h[j] = (short)hh;
        lo[j] = (short)f2bf(vv[j] - bf2f(hh));
    }
    *(bf16x8*)&khp[dst] = h;
    *(bf16x8*)&klp[dst] = lo;
}

// ---------------- prep: V -> transposed swizzled bf16 hi/lo planes [bh][d][key]
__global__ __launch_bounds__(256) void vtprep_kernel(const float* __restrict__ vin,
    unsigned short* __restrict__ vth, unsigned short* __restrict__ vtl) {
    __shared__ __align__(16) unsigned short Th[64][72];
    __shared__ __align__(16) unsigned short Tl[64][72];
    int bh = blockIdx.x;
    int kv0 = blockIdx.y * 64;
    int tid = threadIdx.x;
#pragma unroll
    for (int p = 0; p < 4; ++p) {
        int key = (tid >> 4) + 16 * p;
        int d0 = (tid & 15) * 4;
        float4 v = *(const float4*)&vin[((size_t)bh * 2048 + kv0 + key) * 64 + d0];
        float vv[4] = {v.x, v.y, v.z, v.w};
#pragma unroll
        for (int j = 0; j < 4; ++j) {
            unsigned short hh = f2bf(vv[j]);
            Th[d0 + j][key] = hh;
            Tl[d0 + j][key] = f2bf(vv[j] - bf2f(hh));
        }
    }
    __syncthreads();
    int d = tid >> 2;
#pragma unroll
    for (int q = 0; q < 2; ++q) {
        int gg = (tid & 3) + 4 * q;
        int gs = gg ^ (d & 7);
        bf16x8 hv = *(const bf16x8*)&Th[d][gs * 8];
        bf16x8 lv = *(const bf16x8*)&Tl[d][gs * 8];
        size_t dst = ((size_t)bh * 64 + d) * 2048 + kv0 + gg * 8;
        *(bf16x8*)&vth[dst] = hv;
        *(bf16x8*)&vtl[dst] = lv;
    }
}

// ---------------- K3: MFMA flash attention, 32x32x16, swapped QK^T ----------------
__device__ __forceinline__ void stage_tile(
    const unsigned short* __restrict__ kh, const unsigned short* __restrict__ kl,
    const unsigned short* __restrict__ vh, const unsigned short* __restrict__ vl,
    unsigned short (*ldsb)[4096], int w, int l, int bh, int kv0) {
    if (w < 2) {
        const unsigned short* gp = (w == 0 ? kh : kl)
            + ((size_t)bh * 2048 + kv0 + (l >> 3)) * 64 + (l & 7) * 8;
        unsigned short* lp = ldsb[w];
#pragma unroll
        for (int i = 0; i < 8; ++i)
            GLL16(gp + i * 512, lp + i * 512);
    } else {
        const unsigned short* gp = (w == 2 ? vh : vl)
            + ((size_t)bh * 64 + (l >> 3)) * 2048 + kv0 + (l & 7) * 8;
        unsigned short* lp = ldsb[w];
#pragma unroll
        for (int i = 0; i < 8; ++i)
            GLL16(gp + (size_t)i * 16384, lp + i * 512);
    }
}

#define QROW(r) ((((r) & 3) + 8 * ((r) >> 2)) + 4 * g)

__global__ __launch_bounds__(256, 2) void attn_mfma(
    const float* __restrict__ q_s,
    const unsigned short* __restrict__ kh, const unsigned short* __restrict__ kl,
    const unsigned short* __restrict__ vh, const unsigned short* __restrict__ vl,
    unsigned short* __restrict__ aout_h, unsigned short* __restrict__ aout_l) {
    __shared__ __align__(16) unsigned short lds[2][4][4096];   // 64 KB
    int bh = blockIdx.x;
    int qi = (int)gridDim.y - 1 - blockIdx.y;
    int tid = threadIdx.x;
    int w = tid >> 6, l = tid & 63;
    int qloc = l & 31, g = l >> 5;
    int q0 = qi * 128;
    int qg = q0 + w * 32 + qloc;

    bf16x8 qf[4];
    {
        const float* qrow = q_s + ((size_t)bh * S_LEN + qg) * HD;
#pragma unroll
        for (int t = 0; t < 4; ++t) {
            float4 u0 = *(const float4*)&qrow[t * 16 + g * 8];
            float4 u1 = *(const float4*)&qrow[t * 16 + g * 8 + 4];
            float vv[8] = {u0.x, u0.y, u0.z, u0.w, u1.x, u1.y, u1.z, u1.w};
            bf16x8 r;
#pragma unroll
            for (int j = 0; j < 8; ++j) r[j] = (short)f2bf(vv[j]);
            qf[t] = r;
        }
    }

    f32x16 o0, o1;
#pragma unroll
    for (int r = 0; r < 16; ++r) { o0[r] = 0.f; o1[r] = 0.f; }
    float m_run = -1e30f, l_run = 0.f;

    int nt = 2 * qi + 2;
    int qwmax = q0 + w * 32 + 31;

    stage_tile(kh, kl, vh, vl, lds[0], w, l, bh, 0);
    __syncthreads();

    for (int t = 0; t < nt; ++t) {
        int kv0 = t * 64;
        int bi = t & 1;
        if (t + 1 < nt)
            stage_tile(kh, kl, vh, vl, lds[bi ^ 1], w, l, bh, (t + 1) * 64);

        if (kv0 <= qwmax) {
            const unsigned short* Khp = lds[bi][0];
            const unsigned short* Klp = lds[bi][1];
            const unsigned short* Vhp = lds[bi][2];
            const unsigned short* Vlp = lds[bi][3];

            f32x16 s0, s1;
#pragma unroll
            for (int r = 0; r < 16; ++r) { s0[r] = 0.f; s1[r] = 0.f; }

            __builtin_amdgcn_s_setprio(1);
#pragma unroll
            for (int tt = 0; tt < 4; ++tt) {
                int gr = ((2 * tt + g) ^ (qloc & 7)) * 8;
                bf16x8 a0h = *(const bf16x8*)&Khp[qloc * 64 + gr];
                bf16x8 a1h = *(const bf16x8*)&Khp[(32 + qloc) * 64 + gr];
                bf16x8 a0l = *(const bf16x8*)&Klp[qloc * 64 + gr];
                bf16x8 a1l = *(const bf16x8*)&Klp[(32 + qloc) * 64 + gr];
                s0 = MFMA32(a0h, qf[tt], s0);
                s0 = MFMA32(a0l, qf[tt], s0);
                s1 = MFMA32(a1h, qf[tt], s1);
                s1 = MFMA32(a1l, qf[tt], s1);
            }
            __builtin_amdgcn_s_setprio(0);

            if (kv0 + 63 > q0 + w * 32) {
#pragma unroll
                for (int r = 0; r < 16; ++r) {
                    int kk = kv0 + QROW(r);
                    if (kk > qg)      s0[r] = -1e30f;
                    if (kk + 32 > qg) s1[r] = -1e30f;
                }
            }

            float mx = s0[0];
#pragma unroll
            for (int r = 1; r < 16; ++r) mx = fmaxf(mx, s0[r]);
#pragma unroll
            for (int r = 0; r < 16; ++r) mx = fmaxf(mx, s1[r]);
            mx = fmaxf(mx, __shfl_xor(mx, 32));
            float mnew = fmaxf(m_run, mx);
            float al = __expf(m_run - mnew);
            m_run = mnew;
            float rs = 0.f;
#pragma unroll
            for (int r = 0; r < 16; ++r) { s0[r] = __expf(s0[r] - mnew); rs += s0[r]; }
#pragma unroll
            for (int r = 0; r < 16; ++r) { s1[r] = __expf(s1[r] - mnew); rs += s1[r]; }
            rs += __shfl_xor(rs, 32);
            l_run = l_run * al + rs;
#pragma unroll
            for (int r = 0; r < 16; ++r) {
                float ar = __shfl(al, QROW(r));
                o0[r] *= ar; o1[r] *= ar;
            }

            __builtin_amdgcn_s_setprio(1);
#pragma unroll
            for (int ks = 0; ks < 4; ++ks) {
                const int b = (ks & 1) * 8;
                unsigned w0, w1, w2, w3;
                if (ks < 2) {
                    w0 = cvtpk(s0[b + 0], s0[b + 1]);
                    w1 = cvtpk(s0[b + 2], s0[b + 3]);
                    w2 = cvtpk(s0[b + 4], s0[b + 5]);
                    w3 = cvtpk(s0[b + 6], s0[b + 7]);
                } else {
                    w0 = cvtpk(s1[b + 0], s1[b + 1]);
                    w1 = cvtpk(s1[b + 2], s1[b + 3]);
                    w2 = cvtpk(s1[b + 4], s1[b + 5]);
                    w3 = cvtpk(s1[b + 6], s1[b + 7]);
                }
                asm("v_permlane32_swap_b32 %0, %1" : "+v"(w0), "+v"(w2));
                asm("v_permlane32_swap_b32 %0, %1" : "+v"(w1), "+v"(w3));
                U4 u; u.u[0] = w0; u.u[1] = w1; u.u[2] = w2; u.u[3] = w3;
                bf16x8 pa = u.v;
                int gr = ((2 * ks + g) ^ (qloc & 7)) * 8;
                bf16x8 v0h = *(const bf16x8*)&Vhp[qloc * 64 + gr];
                bf16x8 v1h = *(const bf16x8*)&Vhp[(32 + qloc) * 64 + gr];
                bf16x8 v0l = *(const bf16x8*)&Vlp[qloc * 64 + gr];
                bf16x8 v1l = *(const bf16x8*)&Vlp[(32 + qloc) * 64 + gr];
                o0 = MFMA32(pa, v0h, o0);
                o0 = MFMA32(pa, v0l, o0);
                o1 = MFMA32(pa, v1h, o1);
                o1 = MFMA32(pa, v1l, o1);
            }
            __builtin_amdgcn_s_setprio(0);
        }
        __syncthreads();
    }

    int bb = bh >> 4, h = bh & 15;
#pragma unroll
    for (int r = 0; r < 16; ++r) {
        float li = __shfl(l_run, QROW(r));
        float inv = 1.f / li;
        int qq = q0 + w * 32 + QROW(r);
        size_t base = ((size_t)(bb * S_LEN + qq)) * D_DIM + h * HD + qloc;
        float v0 = o0[r] * inv;
        float v1 = o1[r] * inv;
        unsigned short h0 = f2bf(v0);
        unsigned short h1 = f2bf(v1);
        aout_h[base]      = h0;
        aout_l[base]      = f2bf(v0 - bf2f(h0));
        aout_h[base + 32] = h1;
        aout_l[base + 32] = f2bf(v1 - bf2f(h1));
    }
}

// ---------------- K3 fallback: f32 flash attention ----------------
#define LSTR 68
__global__ __launch_bounds__(256) void attn_kernel(const float* __restrict__ q_s,
    const float* __restrict__ k_s, const float* __restrict__ v_s,
    float* __restrict__ a_s) {
    __shared__ float Qt[64][LSTR];
    __shared__ float KP[64][LSTR];
    __shared__ float Vs[64][LSTR];
    int bh = blockIdx.x;
    int qi = 31 - blockIdx.y;
    int tid = threadIdx.x;
    int tx = tid & 15, ty = tid >> 4;

#pragma unroll
    for (int qq = 0; qq < 4; ++qq) {
        int q  = qq * 16 + (tid >> 4);
        int d4 = (tid & 15) * 4;
        float4 v = *(const float4*)&q_s[((size_t)bh * S_LEN + qi * 64 + q) * HD + d4];
        Qt[d4 + 0][q] = v.x; Qt[d4 + 1][q] = v.y;
        Qt[d4 + 2][q] = v.z; Qt[d4 + 3][q] = v.w;
    }

    float o[4][4];
#pragma unroll
    for (int r = 0; r < 4; ++r)
#pragma unroll
        for (int c = 0; c < 4; ++c) o[r][c] = 0.f;
    float mrow[4] = {-1e30f, -1e30f, -1e30f, -1e30f};
    float lrow[4] = {0.f, 0.f, 0.f, 0.f};

    for (int kt = 0; kt <= qi; ++kt) {
        __syncthreads();
#pragma unroll
        for (int kk2 = 0; kk2 < 4; ++kk2) {
            int k  = kk2 * 16 + (tid >> 4);
            int d4 = (tid & 15) * 4;
            size_t rowoff = ((size_t)bh * S_LEN + kt * 64 + k) * HD + d4;
            float4 kv4 = *(const float4*)&k_s[rowoff];
            KP[d4 + 0][k] = kv4.x; KP[d4 + 1][k] = kv4.y;
            KP[d4 + 2][k] = kv4.z; KP[d4 + 3][k] = kv4.w;
            float4 vv4 = *(const float4*)&v_s[rowoff];
            *(float4*)&Vs[k][d4] = vv4;
        }
        __syncthreads();

        float s[4][4];
#pragma unroll
        for (int r = 0; r < 4; ++r)
#pragma unroll
            for (int c = 0; c < 4; ++c) s[r][c] = 0.f;
#pragma unroll 8
        for (int d = 0; d < 64; ++d) {
            float4 qv = *(const float4*)&Qt[d][ty * 4];
            float4 kv = *(const float4*)&KP[d][tx * 4];
            float qa[4] = {qv.x, qv.y, qv.z, qv.w};
            float ka[4] = {kv.x, kv.y, kv.z, kv.w};
#pragma unroll
            for (int r = 0; r < 4; ++r)
#pragma unroll
                for (int c = 0; c < 4; ++c)
                    s[r][c] = fmaf(qa[r], ka[c], s[r][c]);
        }
        if (kt == qi) {
#pragma unroll
            for (int r = 0; r < 4; ++r)
#pragma unroll
                for (int c = 0; c < 4; ++c)
                    if (tx * 4 + c > ty * 4 + r) s[r][c] = -1e30f;
        }
        __syncthreads();

        float p[4][4];
#pragma unroll
        for (int r = 0; r < 4; ++r) {
            float mx = fmaxf(fmaxf(s[r][0], s[r][1]), fmaxf(s[r][2], s[r][3]));
            mx = fmaxf(mx, __shfl_xor(mx, 1));
            mx = fmaxf(mx, __shfl_xor(mx, 2));
            mx = fmaxf(mx, __shfl_xor(mx, 4));
            mx = fmaxf(mx, __shfl_xor(mx, 8));
            float mn = fmaxf(mrow[r], mx);
            float alpha = __expf(mrow[r] - mn);
            mrow[r] = mn;
            float rsum = 0.f;
#pragma unroll
            for (int c = 0; c < 4; ++c) {
                p[r][c] = __expf(s[r][c] - mn);
                rsum += p[r][c];
            }
            rsum += __shfl_xor(rsum, 1);
            rsum += __shfl_xor(rsum, 2);
            rsum += __shfl_xor(rsum, 4);
            rsum += __shfl_xor(rsum, 8);
            lrow[r] = lrow[r] * alpha + rsum;
#pragma unroll
            for (int c = 0; c < 4; ++c) o[r][c] *= alpha;
            *(float4*)&KP[ty * 4 + r][tx * 4] =
                make_float4(p[r][0], p[r][1], p[r][2], p[r][3]);
        }
        __syncthreads();

#pragma unroll 8
        for (int k = 0; k < 64; ++k) {
            float4 vv = *(const float4*)&Vs[k][tx * 4];
            float va[4] = {vv.x, vv.y, vv.z, vv.w};
#pragma unroll
            for (int r = 0; r < 4; ++r) {
                float pr = KP[ty * 4 + r][k];
#pragma unroll
                for (int c = 0; c < 4; ++c)
                    o[r][c] = fmaf(pr, va[c], o[r][c]);
            }
        }
    }

    int b = bh >> 4, h = bh & 15;
#pragma unroll
    for (int r = 0; r < 4; ++r) {
        int i = qi * 64 + ty * 4 + r;
        float inv = 1.f / lrow[r];
        *(float4*)&a_s[((size_t)(b * S_LEN + i)) * D_DIM + h * HD + tx * 4] =
            make_float4(o[r][0] * inv, o[r][1] * inv, o[r][2] * inv, o[r][3] * inv);
    }
}

// ------ K2 fallback (old fp32 path) ------
__global__ __launch_bounds__(256) void qkv_kernel(const float* __restrict__ x,
    const float* __restrict__ w, const float* __restrict__ bias,
    const float* __restrict__ qa2, const float* __restrict__ va2,
    const float* __restrict__ tq, const float* __restrict__ tv,
    float* __restrict__ qstage, float* __restrict__ pres) {
    __shared__ float As[128][17];
    __shared__ float Bs[16][64];
    int bx = blockIdx.x;
    int by = blockIdx.y;
    int tid = threadIdx.x;
    int tx = tid & 15, ty = tid >> 4;

    float c[8][4];
#pragma unroll
    for (int i = 0; i < 8; ++i)
#pragma unroll
        for (int j = 0; j < 4; ++j) c[i][j] = 0.f;

    for (int k0 = 0; k0 < D_DIM; k0 += 16) {
#pragma unroll
        for (int u = 0; u < 2; ++u) {
            int f4 = tid + 256 * u;
            int row = f4 >> 2;
            int kk4 = (f4 & 3) * 4;
            float4 av = *(const float4*)&x[(size_t)(by * 128 + row) * D_DIM + k0 + kk4];
            As[row][kk4 + 0] = av.x; As[row][kk4 + 1] = av.y;
            As[row][kk4 + 2] = av.z; As[row][kk4 + 3] = av.w;
        }
        {
            int kkb = tid >> 4;
            int col4 = (tid & 15) * 4;
            *(float4*)&Bs[kkb][col4] =
                *(const float4*)&w[(size_t)(k0 + kkb) * N3 + bx * 64 + col4];
        }
        __syncthreads();
#pragma unroll
        for (int kk = 0; kk < 16; ++kk) {
            float4 bv = *(const float4*)&Bs[kk][tx * 4];
#pragma unroll
            for (int i = 0; i < 8; ++i) {
                float a = As[ty * 8 + i][kk];
                c[i][0] = fmaf(a, bv.x, c[i][0]);
                c[i][1] = fmaf(a, bv.y, c[i][1]);
                c[i][2] = fmaf(a, bv.z, c[i][2]);
                c[i][3] = fmaf(a, bv.w, c[i][3]);
            }
        }
        __syncthreads();
    }

    int seg = bx >> 4;
    int h = bx & 15;
    int ncol = bx * 64 + tx * 4;
    float4 bias4 = *(const float4*)&bias[ncol];
    int nloc = h * 64 + tx * 4;

    float4 arr[16];
    if (seg != 1) {
        const float* a2 = (seg == 0 ? qa2 : va2);
#pragma unroll
        for (int jj = 0; jj < 16; ++jj)
            arr[jj] = *(const float4*)&a2[jj * D_DIM + nloc];
    }

#pragma unroll
    for (int i = 0; i < 8; ++i) {
        int t = by * 128 + ty * 8 + i;
        float v0 = c[i][0] + bias4.x;
        float v1 = c[i][1] + bias4.y;
        float v2 = c[i][2] + bias4.z;
        float v3 = c[i][3] + bias4.w;
        if (seg != 1) {
            const float* trow = (seg == 0 ? tq : tv) + t * 16;
            float l0 = 0.f, l1 = 0.f, l2 = 0.f, l3 = 0.f;
#pragma unroll
            for (int jj = 0; jj < 16; ++jj) {
                float tvv = trow[jj];
                l0 = fmaf(tvv, arr[jj].x, l0);
                l1 = fmaf(tvv, arr[jj].y, l1);
                l2 = fmaf(tvv, arr[jj].z, l2);
                l3 = fmaf(tvv, arr[jj].w, l3);
            }
            v0 += 0.5f * l0; v1 += 0.5f * l1; v2 += 0.5f * l2; v3 += 0.5f * l3;
        }
        int b = t >> 11, sidx = t & 2047;
        size_t idx = (((size_t)(b * NH + h) * S_LEN + sidx) * HD) + tx * 4;
        if (seg == 0) {
            *(float4*)&qstage[idx] = make_float4(v0 * 0.125f, v1 * 0.125f,
                                                 v2 * 0.125f, v3 * 0.125f);
        } else if (seg == 1) {
            *(float4*)&pres[idx] = make_float4(v0, v1, v2, v3);
        } else {
            *(float4*)&pres[OUT_KV_ELEMS + idx] = make_float4(v0, v1, v2, v3);
        }
    }
}

// ---------------- K4 fallback: f32 proj ----------------
__global__ __launch_bounds__(256) void proj_kernel(const float* __restrict__ A,
    const float* __restrict__ w, const float* __restrict__ bias,
    float* __restrict__ outp) {
    __shared__ float As[128][17];
    __shared__ float Bs[16][64];
    int bx = blockIdx.x;
    int by = blockIdx.y;
    int tid = threadIdx.x;
    int tx = tid & 15, ty = tid >> 4;

    float c[8][4];
#pragma unroll
    for (int i = 0; i < 8; ++i)
#pragma unroll
        for (int j = 0; j < 4; ++j) c[i][j] = 0.f;

    for (int k0 = 0; k0 < D_DIM; k0 += 16) {
#pragma unroll
        for (int u = 0; u < 2; ++u) {
            int f4 = tid + 256 * u;
            int row = f4 >> 2;
            int kk4 = (f4 & 3) * 4;
            float4 av = *(const float4*)&A[(size_t)(by * 128 + row) * D_DIM + k0 + kk4];
            As[row][kk4 + 0] = av.x; As[row][kk4 + 1] = av.y;
            As[row][kk4 + 2] = av.z; As[row][kk4 + 3] = av.w;
        }
        {
            int kkb = tid >> 4;
            int col4 = (tid & 15) * 4;
            *(float4*)&Bs[kkb][col4] =
                *(const float4*)&w[(size_t)(k0 + kkb) * D_DIM + bx * 64 + col4];
        }
        __syncthreads();
#pragma unroll
        for (int kk = 0; kk < 16; ++kk) {
            float4 bv = *(const float4*)&Bs[kk][tx * 4];
#pragma unroll
            for (int i = 0; i < 8; ++i) {
                float a = As[ty * 8 + i][kk];
                c[i][0] = fmaf(a, bv.x, c[i][0]);
                c[i][1] = fmaf(a, bv.y, c[i][1]);
                c[i][2] = fmaf(a, bv.z, c[i][2]);
                c[i][3] = fmaf(a, bv.w, c[i][3]);
            }
        }
        __syncthreads();
    }

    int ncol = bx * 64 + tx * 4;
    float4 bias4 = *(const float4*)&bias[ncol];
#pragma unroll
    for (int i = 0; i < 8; ++i) {
        int t = by * 128 + ty * 8 + i;
        *(float4*)&outp[(size_t)t * D_DIM + ncol] =
            make_float4(c[i][0] + bias4.x, c[i][1] + bias4.y,
                        c[i][2] + bias4.z, c[i][3] + bias4.w);
    }
}

extern "C" void kernel_launch(void* const* d_in, const int* in_sizes, int n_in,
                              void* d_out, int out_size, void* d_ws, size_t ws_size,
                              hipStream_t stream) {
    const float* x        = (const float*)d_in[0];
    const float* c_attn_w = (const float*)d_in[1];
    const float* c_attn_b = (const float*)d_in[2];
    const float* c_proj_w = (const float*)d_in[3];
    const float* c_proj_b = (const float*)d_in[4];
    const float* q_a1     = (const float*)d_in[5];
    const float* q_a2     = (const float*)d_in[6];
    const float* v_a1     = (const float*)d_in[7];
    const float* v_a2     = (const float*)d_in[8];

    float* outf   = (float*)d_out;
    float* qstage = outf;                  // a-region reused as f32 q staging [B,H,S,hd]
    float* pres   = outf + OUT_A_ELEMS;    // present [2,B,H,S,hd] f32

    // workspace layout:
    //  phase A (pre-qkv):   tq[0,256K) tv[256K,512K) wt[512K,13.5M) a planes[13.5M,30.8M)
    //  phase B (attn):      kp_h[0,8M) kp_l[8,16M) vt_h[16,24M) vt_l[24,32M)
    //  attn out planes:     aout_h[32M,40M) aout_l[40M,48M)
    //  phase C (proj):      wp_h[0,2M) wp_l[2M,4M)   (kp region dead after attn)
    char* wsb = (char*)d_ws;
    float* tq = (float*)wsb;
    float* tv = (float*)(wsb + 262144);
    unsigned short* wt_hi = (unsigned short*)(wsb + 524288);
    unsigned short* wt_lo = (unsigned short*)(wsb + 524288 + 6488064);
    unsigned short* a_hi  = (unsigned short*)(wsb + 13500416);
    unsigned short* a_lo  = (unsigned short*)(wsb + 13500416 + 8650752);
    unsigned short* kp_h  = (unsigned short*)wsb;
    unsigned short* kp_l  = (unsigned short*)(wsb + 8388608);
    unsigned short* vt_h  = (unsigned short*)(wsb + 16777216);
    unsigned short* vt_l  = (unsigned short*)(wsb + 25165824);
    unsigned short* aout_h = (unsigned short*)(wsb + 33554432);
    unsigned short* aout_l = (unsigned short*)(wsb + 41943040);
    unsigned short* wp_h  = (unsigned short*)wsb;
    unsigned short* wp_l  = (unsigned short*)(wsb + 2097152);
    const size_t WS_FULL = 50331648;
    const size_t WS_MID  = 30801920;

    lora1_v2<<<dim3(1024), dim3(256), 0, stream>>>(x, q_a1, v_a1, tq, tv);

    if (ws_size >= WS_FULL) {
        splitA_kernel<<<dim3((T_TOK * (KAUG / 4) + 255) / 256), dim3(256), 0, stream>>>(
            x, tq, tv, a_hi, a_lo);
        splitW_kernel<<<dim3(48, KAUG / 32), dim3(256), 0, stream>>>(
            c_attn_w, q_a2, v_a2, wt_hi, wt_lo);
        qkv_mfma<<<dim3(24, 32), dim3(256), 0, stream>>>(
            a_hi, a_lo, wt_hi, wt_lo, c_attn_b, qstage, pres);
        kprep_kernel<<<dim3(2048), dim3(256), 0, stream>>>(pres, kp_h, kp_l);
        vtprep_kernel<<<dim3(32, 32), dim3(256), 0, stream>>>(
            pres + OUT_KV_ELEMS, vt_h, vt_l);
        attn_mfma<<<dim3(32, 16), dim3(256), 0, stream>>>(
            qstage, kp_h, kp_l, vt_h, vt_l, aout_h, aout_l);
        wprep_kernel<<<dim3(16, 32), dim3(256), 0, stream>>>(c_proj_w, wp_h, wp_l);
        proj_mfma<<<dim3(8, 32), dim3(256), 0, stream>>>(
            aout_h, aout_l, wp_h, wp_l, c_proj_b, outf);
    } else if (ws_size >= WS_MID) {
        float* a_s = (float*)(wsb + 13500416);
        splitA_kernel<<<dim3((T_TOK * (KAUG / 4) + 255) / 256), dim3(256), 0, stream>>>(
            x, tq, tv, a_hi, a_lo);
        splitW_kernel<<<dim3(48, KAUG / 32), dim3(256), 0, stream>>>(
            c_attn_w, q_a2, v_a2, wt_hi, wt_lo);
        qkv_mfma<<<dim3(24, 32), dim3(256), 0, stream>>>(
            a_hi, a_lo, wt_hi, wt_lo, c_attn_b, qstage, pres);
        attn_kernel<<<dim3(32, 32), dim3(256), 0, stream>>>(
            qstage, pres, pres + OUT_KV_ELEMS, a_s);
        proj_kernel<<<dim3(16, 32), dim3(256), 0, stream>>>(
            a_s, c_proj_w, c_proj_b, outf);
    } else {
        float* a_s2 = tv + 65536;
        qkv_kernel<<<dim3(48, 32), dim3(256), 0, stream>>>(x, c_attn_w, c_attn_b,
            q_a2, v_a2, tq, tv, qstage, pres);
        attn_kernel<<<dim3(32, 32), dim3(256), 0, stream>>>(
            qstage, pres, pres + OUT_KV_ELEMS, a_s2);
        proj_kernel<<<dim3(16, 32), dim3(256), 0, stream>>>(
            a_s2, c_proj_w, c_proj_b, outf);
    }
}